// Round 1
// baseline (1181.699 us; speedup 1.0000x reference)
//
#include <hip/hip_runtime.h>
#include <math.h>

#define NROWS 2048
#define HD 512
#define DBx 128
#define DCx 16

// ---------------------------------------------------------------------------
// Generic tiled f32 GEMM: C[N,M] = act(A[N,K] @ W[K,M] + bias[M])
// 64x64 tile, BK=16, 256 threads, 4x4 micro-tile per thread.
// Requires N%64==0, M%64==0, K%16==0 (true for all shapes here).
// ---------------------------------------------------------------------------
template<bool RELU, bool BIAS>
__global__ __launch_bounds__(256) void gemm_kernel(const float* __restrict__ A,
                                                   const float* __restrict__ W,
                                                   const float* __restrict__ bias,
                                                   float* __restrict__ C,
                                                   int K, int M) {
    __shared__ float As[16][64];   // [k][row]
    __shared__ float Ws[16][64];   // [k][col]

    const int t   = threadIdx.x;
    const int tx  = t & 15;        // col group
    const int ty  = t >> 4;        // row group
    const int row0 = blockIdx.y * 64;
    const int col0 = blockIdx.x * 64;

    // load-index mapping
    const int la_row = t >> 2;          // 0..63
    const int la_k   = (t & 3) * 4;     // 0,4,8,12
    const int lw_k   = t >> 4;          // 0..15
    const int lw_col = (t & 15) * 4;    // 0..60

    float acc[4][4] = {};

    for (int k0 = 0; k0 < K; k0 += 16) {
        const float4 av = *reinterpret_cast<const float4*>(
            &A[(size_t)(row0 + la_row) * K + k0 + la_k]);
        const float4 wv = *reinterpret_cast<const float4*>(
            &W[(size_t)(k0 + lw_k) * M + col0 + lw_col]);
        __syncthreads();
        As[la_k + 0][la_row] = av.x;
        As[la_k + 1][la_row] = av.y;
        As[la_k + 2][la_row] = av.z;
        As[la_k + 3][la_row] = av.w;
        *reinterpret_cast<float4*>(&Ws[lw_k][lw_col]) = wv;
        __syncthreads();

        #pragma unroll
        for (int kk = 0; kk < 16; ++kk) {
            const float4 a = *reinterpret_cast<const float4*>(&As[kk][ty * 4]);
            const float4 b = *reinterpret_cast<const float4*>(&Ws[kk][tx * 4]);
            const float ar[4] = {a.x, a.y, a.z, a.w};
            const float br[4] = {b.x, b.y, b.z, b.w};
            #pragma unroll
            for (int r = 0; r < 4; ++r)
                #pragma unroll
                for (int c = 0; c < 4; ++c)
                    acc[r][c] = fmaf(ar[r], br[c], acc[r][c]);
        }
    }

    #pragma unroll
    for (int r = 0; r < 4; ++r) {
        const int row = row0 + ty * 4 + r;
        float4 v = make_float4(acc[r][0], acc[r][1], acc[r][2], acc[r][3]);
        if (BIAS) {
            const float4 bv = *reinterpret_cast<const float4*>(&bias[col0 + tx * 4]);
            v.x += bv.x; v.y += bv.y; v.z += bv.z; v.w += bv.w;
        }
        if (RELU) {
            v.x = fmaxf(v.x, 0.f); v.y = fmaxf(v.y, 0.f);
            v.z = fmaxf(v.z, 0.f); v.w = fmaxf(v.w, 0.f);
        }
        *reinterpret_cast<float4*>(&C[(size_t)row * M + col0 + tx * 4]) = v;
    }
}

// ---------------------------------------------------------------------------
// Minibatch discrimination:
// outT[i,b] = sum_j exp(-sum_c |Ms[i,b,c]-Ms[j,b,c]|)
// Ms: [N, DB*DC] row-major. Grid: (N/256, DB), 256 threads (one i per thread).
// ---------------------------------------------------------------------------
__global__ __launch_bounds__(256) void mbdisc_kernel(const float* __restrict__ Ms,
                                                     float* __restrict__ outT) {
    const int b  = blockIdx.y;
    const int t  = threadIdx.x;
    const int i  = blockIdx.x * 256 + t;

    float mi[16];
    {
        const float* mp = Ms + (size_t)i * (DBx * DCx) + b * DCx;
        #pragma unroll
        for (int c = 0; c < 16; c += 4) {
            const float4 v = *reinterpret_cast<const float4*>(mp + c);
            mi[c] = v.x; mi[c + 1] = v.y; mi[c + 2] = v.z; mi[c + 3] = v.w;
        }
    }

    __shared__ float sj[64][16];
    float acc0 = 0.f, acc1 = 0.f;

    for (int j0 = 0; j0 < NROWS; j0 += 64) {
        __syncthreads();
        {
            const int jr = t >> 2;
            const int cc = (t & 3) * 4;
            const float4 v = *reinterpret_cast<const float4*>(
                Ms + (size_t)(j0 + jr) * (DBx * DCx) + b * DCx + cc);
            *reinterpret_cast<float4*>(&sj[jr][cc]) = v;
        }
        __syncthreads();

        #pragma unroll 4
        for (int jj = 0; jj < 64; jj += 2) {
            // tree-sum the 16 abs-diffs to shorten the dependency chain
            float p0 = 0.f, p1 = 0.f, p2 = 0.f, p3 = 0.f;
            float q0 = 0.f, q1 = 0.f, q2 = 0.f, q3 = 0.f;
            #pragma unroll
            for (int c = 0; c < 16; c += 4) {
                p0 += fabsf(mi[c + 0] - sj[jj][c + 0]);
                p1 += fabsf(mi[c + 1] - sj[jj][c + 1]);
                p2 += fabsf(mi[c + 2] - sj[jj][c + 2]);
                p3 += fabsf(mi[c + 3] - sj[jj][c + 3]);
                q0 += fabsf(mi[c + 0] - sj[jj + 1][c + 0]);
                q1 += fabsf(mi[c + 1] - sj[jj + 1][c + 1]);
                q2 += fabsf(mi[c + 2] - sj[jj + 1][c + 2]);
                q3 += fabsf(mi[c + 3] - sj[jj + 1][c + 3]);
            }
            const float d0 = (p0 + p1) + (p2 + p3);
            const float d1 = (q0 + q1) + (q2 + q3);
            acc0 += __expf(-d0);
            acc1 += __expf(-d1);
        }
    }
    outT[(size_t)i * DBx + b] = acc0 + acc1;
}

// ---------------------------------------------------------------------------
// logits = sigmoid(concat(feature, outT) @ Wo + bo). One block per row.
// ---------------------------------------------------------------------------
__global__ __launch_bounds__(256) void logits_kernel(const float* __restrict__ feat,
                                                     const float* __restrict__ outT,
                                                     const float* __restrict__ Wo,
                                                     const float* __restrict__ bo,
                                                     float* __restrict__ out2) {
    const int row = blockIdx.x;
    const int t   = threadIdx.x;
    float p = 0.f;
    for (int k = t; k < HD + DBx; k += 256) {
        const float x = (k < HD) ? feat[(size_t)row * HD + k]
                                 : outT[(size_t)row * DBx + (k - HD)];
        p += x * Wo[k];
    }
    #pragma unroll
    for (int off = 32; off; off >>= 1) p += __shfl_down(p, off, 64);
    __shared__ float ws[4];
    if ((t & 63) == 0) ws[t >> 6] = p;
    __syncthreads();
    if (t == 0) {
        const float s = ws[0] + ws[1] + ws[2] + ws[3] + bo[0];
        out2[row] = 1.f / (1.f + __expf(-s));
    }
}

// ---------------------------------------------------------------------------
extern "C" void kernel_launch(void* const* d_in, const int* in_sizes, int n_in,
                              void* d_out, int out_size, void* d_ws, size_t ws_size,
                              hipStream_t stream) {
    const float* input = (const float*)d_in[0];
    const float* W1 = (const float*)d_in[1];
    const float* b1 = (const float*)d_in[2];
    const float* W2 = (const float*)d_in[3];
    const float* b2 = (const float*)d_in[4];
    const float* Wh = (const float*)d_in[5];
    const float* bh = (const float*)d_in[6];
    const float* W3 = (const float*)d_in[7];
    const float* b3 = (const float*)d_in[8];
    const float* W4 = (const float*)d_in[9];
    const float* b4 = (const float*)d_in[10];
    const float* Wo = (const float*)d_in[11];
    const float* bo = (const float*)d_in[12];
    const float* T  = (const float*)d_in[13];

    float* x1 = (float*)d_ws;                        // [2048,1024]  8 MB
    float* x2 = x1 + (size_t)NROWS * 1024;           // [2048,1536] 12 MB
    float* x3 = x2 + (size_t)NROWS * 1536;           // [2048,1536] 12 MB
    float* x4 = x1;                                  // reuse x1 (dead) [2048,1024]
    float* Ms = x3 + (size_t)NROWS * 1536;           // [2048,2048] 16 MB
    float* oT = Ms + (size_t)NROWS * 2048;           // [2048,128]   1 MB

    float* feat = (float*)d_out;                     // [2048,512]
    float* out2 = feat + (size_t)NROWS * HD;         // [2048,1]

    const dim3 blk(256);
    gemm_kernel<true, true ><<<dim3(1024 / 64, NROWS / 64), blk, 0, stream>>>(input, W1, b1, x1, 512, 1024);
    gemm_kernel<true, true ><<<dim3(1536 / 64, NROWS / 64), blk, 0, stream>>>(x1, W2, b2, x2, 1024, 1536);
    gemm_kernel<true, true ><<<dim3(1536 / 64, NROWS / 64), blk, 0, stream>>>(x2, Wh, bh, x3, 1536, 1536);
    gemm_kernel<true, true ><<<dim3(1024 / 64, NROWS / 64), blk, 0, stream>>>(x3, W3, b3, x4, 1536, 1024);
    gemm_kernel<true, true ><<<dim3( 512 / 64, NROWS / 64), blk, 0, stream>>>(x4, W4, b4, feat, 1536 == 1536 ? 1024 : 1024, 512);
    gemm_kernel<false, false><<<dim3(2048 / 64, NROWS / 64), blk, 0, stream>>>(feat, T, nullptr, Ms, 512, 2048);

    mbdisc_kernel<<<dim3(NROWS / 256, DBx), blk, 0, stream>>>(Ms, oT);
    logits_kernel<<<NROWS, blk, 0, stream>>>(feat, oT, Wo, bo, out2);
}

// Round 2
// 898.843 us; speedup vs baseline: 1.3147x; 1.3147x over previous
//
#include <hip/hip_runtime.h>
#include <math.h>

#define NROWS 2048
#define HD 512
#define DBx 128
#define DCx 16

// ---------------------------------------------------------------------------
// f32 GEMM, 64x64 tile, BK=16, 256 threads, 4x4 micro-tile (used for M=512).
// ---------------------------------------------------------------------------
template<bool RELU, bool BIAS>
__global__ __launch_bounds__(256) void gemm_kernel(const float* __restrict__ A,
                                                   const float* __restrict__ W,
                                                   const float* __restrict__ bias,
                                                   float* __restrict__ C,
                                                   int K, int M) {
    __shared__ float As[16][64];   // [k][row]
    __shared__ float Ws[16][64];   // [k][col]

    const int t   = threadIdx.x;
    const int tx  = t & 15;
    const int ty  = t >> 4;
    const int row0 = blockIdx.y * 64;
    const int col0 = blockIdx.x * 64;

    const int la_row = t >> 2;
    const int la_k   = (t & 3) * 4;
    const int lw_k   = t >> 4;
    const int lw_col = (t & 15) * 4;

    float acc[4][4] = {};

    for (int k0 = 0; k0 < K; k0 += 16) {
        const float4 av = *reinterpret_cast<const float4*>(
            &A[(size_t)(row0 + la_row) * K + k0 + la_k]);
        const float4 wv = *reinterpret_cast<const float4*>(
            &W[(size_t)(k0 + lw_k) * M + col0 + lw_col]);
        __syncthreads();
        As[la_k + 0][la_row] = av.x;
        As[la_k + 1][la_row] = av.y;
        As[la_k + 2][la_row] = av.z;
        As[la_k + 3][la_row] = av.w;
        *reinterpret_cast<float4*>(&Ws[lw_k][lw_col]) = wv;
        __syncthreads();

        #pragma unroll
        for (int kk = 0; kk < 16; ++kk) {
            const float4 a = *reinterpret_cast<const float4*>(&As[kk][ty * 4]);
            const float4 b = *reinterpret_cast<const float4*>(&Ws[kk][tx * 4]);
            const float ar[4] = {a.x, a.y, a.z, a.w};
            const float br[4] = {b.x, b.y, b.z, b.w};
            #pragma unroll
            for (int r = 0; r < 4; ++r)
                #pragma unroll
                for (int c = 0; c < 4; ++c)
                    acc[r][c] = fmaf(ar[r], br[c], acc[r][c]);
        }
    }

    #pragma unroll
    for (int r = 0; r < 4; ++r) {
        const int row = row0 + ty * 4 + r;
        float4 v = make_float4(acc[r][0], acc[r][1], acc[r][2], acc[r][3]);
        if (BIAS) {
            const float4 bv = *reinterpret_cast<const float4*>(&bias[col0 + tx * 4]);
            v.x += bv.x; v.y += bv.y; v.z += bv.z; v.w += bv.w;
        }
        if (RELU) {
            v.x = fmaxf(v.x, 0.f); v.y = fmaxf(v.y, 0.f);
            v.z = fmaxf(v.z, 0.f); v.w = fmaxf(v.w, 0.f);
        }
        *reinterpret_cast<float4*>(&C[(size_t)row * M + col0 + tx * 4]) = v;
    }
}

// ---------------------------------------------------------------------------
// f32 GEMM, 128(rows) x 64(cols) tile, BK=16, 256 threads, 8x4 micro-tile.
// Better FMA : LDS-read ratio (32:3 per kk). Requires M%64==0, K%16, N%128.
// ---------------------------------------------------------------------------
template<bool RELU, bool BIAS>
__global__ __launch_bounds__(256) void gemm128x64_kernel(const float* __restrict__ A,
                                                         const float* __restrict__ W,
                                                         const float* __restrict__ bias,
                                                         float* __restrict__ C,
                                                         int K, int M) {
    __shared__ float As[16][128];  // [k][row]
    __shared__ float Ws[16][64];   // [k][col]

    const int t   = threadIdx.x;
    const int tx  = t & 15;        // col group: cols tx*4..+4
    const int ty  = t >> 4;        // row group: rows ty*4..+4 and 64+ty*4..+4
    const int row0 = blockIdx.y * 128;
    const int col0 = blockIdx.x * 64;

    // A staging: 128 rows x 16 k = 512 float4; 2 per thread.
    // q in {2t, 2t+1}: row = q>>2, k = (q&3)*4
    // W staging: 16 k x 64 cols = 256 float4; 1 per thread: k=t>>4, c=(t&15)*4
    const int wk = t >> 4;
    const int wc = (t & 15) * 4;

    float acc[8][4] = {};

    for (int k0 = 0; k0 < K; k0 += 16) {
        float4 av[2];
        #pragma unroll
        for (int qq = 0; qq < 2; ++qq) {
            const int q  = t * 2 + qq;
            const int ar = q >> 2;
            const int ak = (q & 3) * 4;
            av[qq] = *reinterpret_cast<const float4*>(
                &A[(size_t)(row0 + ar) * K + k0 + ak]);
        }
        const float4 wv = *reinterpret_cast<const float4*>(
            &W[(size_t)(k0 + wk) * M + col0 + wc]);
        __syncthreads();
        #pragma unroll
        for (int qq = 0; qq < 2; ++qq) {
            const int q  = t * 2 + qq;
            const int ar = q >> 2;
            const int ak = (q & 3) * 4;
            As[ak + 0][ar] = av[qq].x;
            As[ak + 1][ar] = av[qq].y;
            As[ak + 2][ar] = av[qq].z;
            As[ak + 3][ar] = av[qq].w;
        }
        *reinterpret_cast<float4*>(&Ws[wk][wc]) = wv;
        __syncthreads();

        #pragma unroll
        for (int kk = 0; kk < 16; ++kk) {
            const float4 a0 = *reinterpret_cast<const float4*>(&As[kk][ty * 4]);
            const float4 a1 = *reinterpret_cast<const float4*>(&As[kk][64 + ty * 4]);
            const float4 b  = *reinterpret_cast<const float4*>(&Ws[kk][tx * 4]);
            const float ar[8] = {a0.x, a0.y, a0.z, a0.w, a1.x, a1.y, a1.z, a1.w};
            const float br[4] = {b.x, b.y, b.z, b.w};
            #pragma unroll
            for (int r = 0; r < 8; ++r)
                #pragma unroll
                for (int c = 0; c < 4; ++c)
                    acc[r][c] = fmaf(ar[r], br[c], acc[r][c]);
        }
    }

    float4 bv = make_float4(0.f, 0.f, 0.f, 0.f);
    if (BIAS) bv = *reinterpret_cast<const float4*>(&bias[col0 + tx * 4]);
    #pragma unroll
    for (int r = 0; r < 8; ++r) {
        const int row = row0 + ((r < 4) ? (ty * 4 + r) : (64 + ty * 4 + r - 4));
        float4 v = make_float4(acc[r][0], acc[r][1], acc[r][2], acc[r][3]);
        if (BIAS) { v.x += bv.x; v.y += bv.y; v.z += bv.z; v.w += bv.w; }
        if (RELU) {
            v.x = fmaxf(v.x, 0.f); v.y = fmaxf(v.y, 0.f);
            v.z = fmaxf(v.z, 0.f); v.w = fmaxf(v.w, 0.f);
        }
        *reinterpret_cast<float4*>(&C[(size_t)row * M + col0 + tx * 4]) = v;
    }
}

// ---------------------------------------------------------------------------
// Minibatch discrimination with provably-safe early exit.
// outT[i,b] = sum_j exp(-d16(i,j,b)),  d16 = sum_c |Ms[i,b,c]-Ms[j,b,c]|.
// Since d16 >= p4 (partial over first 4 c's), if p4 >= 36 for ALL lanes the
// whole wave's terms are < e^-36 ~ 2e-16 and can be skipped (error < 5e-13
// for any input). Fast path: 1 broadcast ds_read_b128 + ~8 VALU per j.
// ---------------------------------------------------------------------------
__global__ __launch_bounds__(256) void mbdisc_kernel(const float* __restrict__ Ms,
                                                     float* __restrict__ outT) {
    const int b  = blockIdx.y;
    const int t  = threadIdx.x;
    const int i  = blockIdx.x * 256 + t;

    float mi[16];
    {
        const float* mp = Ms + (size_t)i * (DBx * DCx) + b * DCx;
        #pragma unroll
        for (int c = 0; c < 16; c += 4) {
            const float4 v = *reinterpret_cast<const float4*>(mp + c);
            mi[c] = v.x; mi[c + 1] = v.y; mi[c + 2] = v.z; mi[c + 3] = v.w;
        }
    }

    __shared__ float sj[64][16];
    float acc = 0.f;

    for (int j0 = 0; j0 < NROWS; j0 += 64) {
        __syncthreads();
        {
            const int jr = t >> 2;
            const int cc = (t & 3) * 4;
            const float4 v = *reinterpret_cast<const float4*>(
                Ms + (size_t)(j0 + jr) * (DBx * DCx) + b * DCx + cc);
            *reinterpret_cast<float4*>(&sj[jr][cc]) = v;
        }
        __syncthreads();

        #pragma unroll 4
        for (int jj = 0; jj < 64; ++jj) {
            const float4 s0 = *reinterpret_cast<const float4*>(&sj[jj][0]);
            const float p = (fabsf(mi[0] - s0.x) + fabsf(mi[1] - s0.y)) +
                            (fabsf(mi[2] - s0.z) + fabsf(mi[3] - s0.w));
            if (__any(p < 36.0f)) {
                const float4 s1 = *reinterpret_cast<const float4*>(&sj[jj][4]);
                const float4 s2 = *reinterpret_cast<const float4*>(&sj[jj][8]);
                const float4 s3 = *reinterpret_cast<const float4*>(&sj[jj][12]);
                const float q0 = (fabsf(mi[4] - s1.x) + fabsf(mi[5] - s1.y)) +
                                 (fabsf(mi[6] - s1.z) + fabsf(mi[7] - s1.w));
                const float q1 = (fabsf(mi[8] - s2.x) + fabsf(mi[9] - s2.y)) +
                                 (fabsf(mi[10] - s2.z) + fabsf(mi[11] - s2.w));
                const float q2 = (fabsf(mi[12] - s3.x) + fabsf(mi[13] - s3.y)) +
                                 (fabsf(mi[14] - s3.z) + fabsf(mi[15] - s3.w));
                acc += __expf(-((p + q0) + (q1 + q2)));
            }
        }
    }
    outT[(size_t)i * DBx + b] = acc;
}

// ---------------------------------------------------------------------------
// logits = sigmoid(concat(feature, outT) @ Wo + bo). One block per row.
// ---------------------------------------------------------------------------
__global__ __launch_bounds__(256) void logits_kernel(const float* __restrict__ feat,
                                                     const float* __restrict__ outT,
                                                     const float* __restrict__ Wo,
                                                     const float* __restrict__ bo,
                                                     float* __restrict__ out2) {
    const int row = blockIdx.x;
    const int t   = threadIdx.x;
    float p = 0.f;
    for (int k = t; k < HD + DBx; k += 256) {
        const float x = (k < HD) ? feat[(size_t)row * HD + k]
                                 : outT[(size_t)row * DBx + (k - HD)];
        p += x * Wo[k];
    }
    #pragma unroll
    for (int off = 32; off; off >>= 1) p += __shfl_down(p, off, 64);
    __shared__ float ws[4];
    if ((t & 63) == 0) ws[t >> 6] = p;
    __syncthreads();
    if (t == 0) {
        const float s = ws[0] + ws[1] + ws[2] + ws[3] + bo[0];
        out2[row] = 1.f / (1.f + __expf(-s));
    }
}

// ---------------------------------------------------------------------------
extern "C" void kernel_launch(void* const* d_in, const int* in_sizes, int n_in,
                              void* d_out, int out_size, void* d_ws, size_t ws_size,
                              hipStream_t stream) {
    const float* input = (const float*)d_in[0];
    const float* W1 = (const float*)d_in[1];
    const float* b1 = (const float*)d_in[2];
    const float* W2 = (const float*)d_in[3];
    const float* b2 = (const float*)d_in[4];
    const float* Wh = (const float*)d_in[5];
    const float* bh = (const float*)d_in[6];
    const float* W3 = (const float*)d_in[7];
    const float* b3 = (const float*)d_in[8];
    const float* W4 = (const float*)d_in[9];
    const float* b4 = (const float*)d_in[10];
    const float* Wo = (const float*)d_in[11];
    const float* bo = (const float*)d_in[12];
    const float* T  = (const float*)d_in[13];

    float* x1 = (float*)d_ws;                        // [2048,1024]
    float* x2 = x1 + (size_t)NROWS * 1024;           // [2048,1536]
    float* x3 = x2 + (size_t)NROWS * 1536;           // [2048,1536]
    float* x4 = x1;                                  // reuse x1 (dead)
    float* Ms = x3 + (size_t)NROWS * 1536;           // [2048,2048]
    float* oT = Ms + (size_t)NROWS * 2048;           // [2048,128]

    float* feat = (float*)d_out;                     // [2048,512]
    float* out2 = feat + (size_t)NROWS * HD;         // [2048,1]

    const dim3 blk(256);
    gemm128x64_kernel<true, true ><<<dim3(1024 / 64, NROWS / 128), blk, 0, stream>>>(input, W1, b1, x1, 512, 1024);
    gemm128x64_kernel<true, true ><<<dim3(1536 / 64, NROWS / 128), blk, 0, stream>>>(x1, W2, b2, x2, 1024, 1536);
    gemm128x64_kernel<true, true ><<<dim3(1536 / 64, NROWS / 128), blk, 0, stream>>>(x2, Wh, bh, x3, 1536, 1536);
    gemm128x64_kernel<true, true ><<<dim3(1024 / 64, NROWS / 128), blk, 0, stream>>>(x3, W3, b3, x4, 1536, 1024);
    gemm_kernel<true, true >      <<<dim3( 512 / 64, NROWS /  64), blk, 0, stream>>>(x4, W4, b4, feat, 1024, 512);
    gemm128x64_kernel<false, false><<<dim3(2048 / 64, NROWS / 128), blk, 0, stream>>>(feat, T, nullptr, Ms, 512, 2048);

    mbdisc_kernel<<<dim3(NROWS / 256, DBx), blk, 0, stream>>>(Ms, oT);
    logits_kernel<<<NROWS, blk, 0, stream>>>(feat, oT, Wo, bo, out2);
}

// Round 3
// 441.871 us; speedup vs baseline: 2.6743x; 2.0342x over previous
//
#include <hip/hip_runtime.h>
#include <hip/hip_bf16.h>
#include <math.h>

#define NROWS 2048
#define HD 512
#define DBx 128
#define DCx 16

typedef __attribute__((ext_vector_type(8))) short bf16x8;
typedef __attribute__((ext_vector_type(4))) float f32x4;

__device__ inline unsigned pack2_bf16(float a, float b) {
    union { __hip_bfloat162 h; unsigned u; } cv;
    cv.h = __float22bfloat162_rn(make_float2(a, b));
    return cv.u;
}
__device__ inline unsigned short pack1_bf16(float a) {
    union { __hip_bfloat16 h; unsigned short u; } cv;
    cv.h = __float2bfloat16(a);
    return cv.u;
}

// ---------------------------------------------------------------------------
// f32 [n] -> bf16 [n] straight conversion (input activations).
// ---------------------------------------------------------------------------
__global__ __launch_bounds__(256) void conv_bf16_kernel(const float* __restrict__ in,
                                                        unsigned short* __restrict__ out,
                                                        int n4) {
    for (int idx = blockIdx.x * 256 + threadIdx.x; idx < n4; idx += gridDim.x * 256) {
        const float4 v = *reinterpret_cast<const float4*>(in + (size_t)idx * 4);
        uint2 o;
        o.x = pack2_bf16(v.x, v.y);
        o.y = pack2_bf16(v.z, v.w);
        *reinterpret_cast<uint2*>(out + (size_t)idx * 4) = o;
    }
}

// ---------------------------------------------------------------------------
// Transpose+convert: W f32 [K][M] -> Wt bf16 [M][K]. 32x32 tiles.
// ---------------------------------------------------------------------------
__global__ __launch_bounds__(256) void conv_transpose_kernel(const float* __restrict__ W,
                                                             unsigned short* __restrict__ Wt,
                                                             int K, int M) {
    __shared__ float tile[32][33];
    const int t  = threadIdx.x;
    const int tr = t >> 3;        // 0..31
    const int tc = t & 7;         // 0..7
    const int k0 = blockIdx.y * 32;
    const int m0 = blockIdx.x * 32;

    const float4 v = *reinterpret_cast<const float4*>(&W[(size_t)(k0 + tr) * M + m0 + tc * 4]);
    tile[tr][tc * 4 + 0] = v.x;
    tile[tr][tc * 4 + 1] = v.y;
    tile[tr][tc * 4 + 2] = v.z;
    tile[tr][tc * 4 + 3] = v.w;
    __syncthreads();

    const float a = tile[tc * 4 + 0][tr];
    const float b = tile[tc * 4 + 1][tr];
    const float c = tile[tc * 4 + 2][tr];
    const float d = tile[tc * 4 + 3][tr];
    uint2 o;
    o.x = pack2_bf16(a, b);
    o.y = pack2_bf16(c, d);
    *reinterpret_cast<uint2*>(&Wt[(size_t)(m0 + tr) * K + k0 + tc * 4]) = o;
}

// ---------------------------------------------------------------------------
// bf16 MFMA GEMM. A bf16 [rows][K], Bt bf16 [M][K] (pre-transposed weights).
// BM=128, BN=64, BK=64. 256 threads = 4 waves (2M x 2N), wave = 64x32 out.
// LDS tiles [row][k], row stride 128B, 16B-chunk XOR swizzle ch^(row&7).
// Staged via global_load_lds(16B) with pre-swizzled per-lane global source.
// ---------------------------------------------------------------------------
template<int WRITE_BF16, int WRITE_F32, int RELU, int BIAS>
__global__ __launch_bounds__(256) void gemm_bf16_kernel(const unsigned short* __restrict__ Abf,
                                                        const unsigned short* __restrict__ Bt,
                                                        const float* __restrict__ bias,
                                                        unsigned short* __restrict__ Cbf,
                                                        float* __restrict__ Cf,
                                                        int K, int M) {
    __shared__ unsigned short As[128 * 64];  // 16 KB
    __shared__ unsigned short Bs[64 * 64];   //  8 KB

    const int t    = threadIdx.x;
    const int lane = t & 63;
    const int wv   = t >> 6;      // 0..3
    const int wm   = wv & 1;      // M half (64 rows)
    const int wn   = wv >> 1;     // N half (32 cols)
    const int row0 = blockIdx.y * 128;
    const int col0 = blockIdx.x * 64;

    const int gl_r = lane >> 3;   // row within 8-row group
    const int gl_c = lane & 7;    // 16B chunk 0..7

    f32x4 acc[4][2] = {};

    for (int kt = 0; kt < K; kt += 64) {
        __syncthreads();  // previous iteration's frag reads complete
        // A tile: wave wv stages rows [wv*32, wv*32+32), 4 instrs x 8 rows
        #pragma unroll
        for (int q = 0; q < 4; ++q) {
            const int r = wv * 32 + q * 8 + gl_r;
            const unsigned short* src = Abf + (size_t)(row0 + r) * K + kt + 8 * (gl_c ^ (r & 7));
            __builtin_amdgcn_global_load_lds(
                (const __attribute__((address_space(1))) void*)src,
                (__attribute__((address_space(3))) void*)(As + (wv * 32 + q * 8) * 64),
                16, 0, 0);
        }
        // B tile: wave wv stages n [wv*16, wv*16+16), 2 instrs x 8 rows
        #pragma unroll
        for (int q = 0; q < 2; ++q) {
            const int n = wv * 16 + q * 8 + gl_r;
            const unsigned short* src = Bt + (size_t)(col0 + n) * K + kt + 8 * (gl_c ^ (n & 7));
            __builtin_amdgcn_global_load_lds(
                (const __attribute__((address_space(1))) void*)src,
                (__attribute__((address_space(3))) void*)(Bs + (wv * 16 + q * 8) * 64),
                16, 0, 0);
        }
        __syncthreads();  // compiler drains vmcnt(0) before barrier

        const int lm = lane & 15;
        const int kg = lane >> 4;
        #pragma unroll
        for (int ks = 0; ks < 2; ++ks) {
            bf16x8 af[4], bfr[2];
            #pragma unroll
            for (int fi = 0; fi < 4; ++fi) {
                const int r  = wm * 64 + fi * 16 + lm;
                const int ch = (kg + 4 * ks) ^ (r & 7);
                af[fi] = *reinterpret_cast<const bf16x8*>((const char*)As + r * 128 + ch * 16);
            }
            #pragma unroll
            for (int fj = 0; fj < 2; ++fj) {
                const int n  = wn * 32 + fj * 16 + lm;
                const int ch = (kg + 4 * ks) ^ (n & 7);
                bfr[fj] = *reinterpret_cast<const bf16x8*>((const char*)Bs + n * 128 + ch * 16);
            }
            #pragma unroll
            for (int fi = 0; fi < 4; ++fi)
                #pragma unroll
                for (int fj = 0; fj < 2; ++fj)
                    acc[fi][fj] = __builtin_amdgcn_mfma_f32_16x16x32_bf16(
                        af[fi], bfr[fj], acc[fi][fj], 0, 0, 0);
        }
    }

    // epilogue: D col = lane&15, row = (lane>>4)*4 + r  [m89-verified]
    const int lm = lane & 15;
    const int lq = lane >> 4;
    #pragma unroll
    for (int fj = 0; fj < 2; ++fj) {
        const int col = col0 + wn * 32 + fj * 16 + lm;
        const float bv = BIAS ? bias[col] : 0.f;
        #pragma unroll
        for (int fi = 0; fi < 4; ++fi) {
            #pragma unroll
            for (int r = 0; r < 4; ++r) {
                const int row = row0 + wm * 64 + fi * 16 + lq * 4 + r;
                float v = acc[fi][fj][r] + bv;
                if (RELU) v = fmaxf(v, 0.f);
                if (WRITE_F32)  Cf[(size_t)row * M + col] = v;
                if (WRITE_BF16) Cbf[(size_t)row * M + col] = pack1_bf16(v);
            }
        }
    }
}

// ---------------------------------------------------------------------------
// Minibatch discrimination with provably-safe early exit (p4 lower bound,
// tau=36: skipped terms < e^-36, total err < 5e-13). j-range split across
// blockIdx.z for occupancy; partial sums combined via atomicAdd (oT zeroed
// by hipMemsetAsync beforehand).
// ---------------------------------------------------------------------------
#define JSPLIT 2
__global__ __launch_bounds__(256) void mbdisc_kernel(const float* __restrict__ Ms,
                                                     float* __restrict__ outT) {
    const int b  = blockIdx.y;
    const int t  = threadIdx.x;
    const int i  = blockIdx.x * 256 + t;
    const int jb = blockIdx.z * (NROWS / JSPLIT);

    float mi[16];
    {
        const float* mp = Ms + (size_t)i * (DBx * DCx) + b * DCx;
        #pragma unroll
        for (int c = 0; c < 16; c += 4) {
            const float4 v = *reinterpret_cast<const float4*>(mp + c);
            mi[c] = v.x; mi[c + 1] = v.y; mi[c + 2] = v.z; mi[c + 3] = v.w;
        }
    }

    __shared__ float sj[64][16];
    float acc = 0.f;

    for (int j0 = jb; j0 < jb + NROWS / JSPLIT; j0 += 64) {
        __syncthreads();
        {
            const int jr = t >> 2;
            const int cc = (t & 3) * 4;
            const float4 v = *reinterpret_cast<const float4*>(
                Ms + (size_t)(j0 + jr) * (DBx * DCx) + b * DCx + cc);
            *reinterpret_cast<float4*>(&sj[jr][cc]) = v;
        }
        __syncthreads();

        #pragma unroll 4
        for (int jj = 0; jj < 64; ++jj) {
            const float4 s0 = *reinterpret_cast<const float4*>(&sj[jj][0]);
            const float p = (fabsf(mi[0] - s0.x) + fabsf(mi[1] - s0.y)) +
                            (fabsf(mi[2] - s0.z) + fabsf(mi[3] - s0.w));
            if (__any(p < 36.0f)) {
                const float4 s1 = *reinterpret_cast<const float4*>(&sj[jj][4]);
                const float4 s2 = *reinterpret_cast<const float4*>(&sj[jj][8]);
                const float4 s3 = *reinterpret_cast<const float4*>(&sj[jj][12]);
                const float q0 = (fabsf(mi[4] - s1.x) + fabsf(mi[5] - s1.y)) +
                                 (fabsf(mi[6] - s1.z) + fabsf(mi[7] - s1.w));
                const float q1 = (fabsf(mi[8] - s2.x) + fabsf(mi[9] - s2.y)) +
                                 (fabsf(mi[10] - s2.z) + fabsf(mi[11] - s2.w));
                const float q2 = (fabsf(mi[12] - s3.x) + fabsf(mi[13] - s3.y)) +
                                 (fabsf(mi[14] - s3.z) + fabsf(mi[15] - s3.w));
                acc += __expf(-((p + q0) + (q1 + q2)));
            }
        }
    }
    atomicAdd(&outT[(size_t)i * DBx + b], acc);
}

// ---------------------------------------------------------------------------
// logits = sigmoid(concat(feature, outT) @ Wo + bo). One block per row.
// ---------------------------------------------------------------------------
__global__ __launch_bounds__(256) void logits_kernel(const float* __restrict__ feat,
                                                     const float* __restrict__ outT,
                                                     const float* __restrict__ Wo,
                                                     const float* __restrict__ bo,
                                                     float* __restrict__ out2) {
    const int row = blockIdx.x;
    const int t   = threadIdx.x;
    float p = 0.f;
    for (int k = t; k < HD + DBx; k += 256) {
        const float x = (k < HD) ? feat[(size_t)row * HD + k]
                                 : outT[(size_t)row * DBx + (k - HD)];
        p += x * Wo[k];
    }
    #pragma unroll
    for (int off = 32; off; off >>= 1) p += __shfl_down(p, off, 64);
    __shared__ float ws[4];
    if ((t & 63) == 0) ws[t >> 6] = p;
    __syncthreads();
    if (t == 0) {
        const float s = ws[0] + ws[1] + ws[2] + ws[3] + bo[0];
        out2[row] = 1.f / (1.f + __expf(-s));
    }
}

// ---------------------------------------------------------------------------
extern "C" void kernel_launch(void* const* d_in, const int* in_sizes, int n_in,
                              void* d_out, int out_size, void* d_ws, size_t ws_size,
                              hipStream_t stream) {
    const float* input = (const float*)d_in[0];
    const float* W1 = (const float*)d_in[1];
    const float* b1 = (const float*)d_in[2];
    const float* W2 = (const float*)d_in[3];
    const float* b2 = (const float*)d_in[4];
    const float* Wh = (const float*)d_in[5];
    const float* bh = (const float*)d_in[6];
    const float* W3 = (const float*)d_in[7];
    const float* b3 = (const float*)d_in[8];
    const float* W4 = (const float*)d_in[9];
    const float* b4 = (const float*)d_in[10];
    const float* Wo = (const float*)d_in[11];
    const float* bo = (const float*)d_in[12];
    const float* T  = (const float*)d_in[13];

    // workspace layout (45.5 MB total)
    char* w = (char*)d_ws;
    unsigned short* inbf = (unsigned short*)w;  w += (size_t)2048 * 512 * 2;   // 2 MB
    unsigned short* W1t  = (unsigned short*)w;  w += (size_t)1024 * 512 * 2;   // 1 MB
    unsigned short* W2t  = (unsigned short*)w;  w += (size_t)1536 * 1024 * 2;  // 3 MB
    unsigned short* Wht  = (unsigned short*)w;  w += (size_t)1536 * 1536 * 2;  // 4.5 MB
    unsigned short* W3t  = (unsigned short*)w;  w += (size_t)1024 * 1536 * 2;  // 3 MB
    unsigned short* W4t  = (unsigned short*)w;  w += (size_t)512 * 1024 * 2;   // 1 MB
    unsigned short* Tt   = (unsigned short*)w;  w += (size_t)2048 * 512 * 2;   // 2 MB
    unsigned short* slabA = (unsigned short*)w; w += (size_t)2048 * 1536 * 2;  // 6 MB
    unsigned short* slabB = (unsigned short*)w; w += (size_t)2048 * 1536 * 2;  // 6 MB
    float* Ms = (float*)w;                      w += (size_t)2048 * 2048 * 4;  // 16 MB
    float* oT = (float*)w;                      w += (size_t)2048 * 128 * 4;   // 1 MB

    unsigned short* x1bf   = slabA;  // [2048][1024]
    unsigned short* x2bf   = slabB;  // [2048][1536]
    unsigned short* x3bf   = slabA;  // [2048][1536] (x1 dead)
    unsigned short* x4bf   = slabB;  // [2048][1024] (x2 dead)
    unsigned short* featbf = slabA;  // [2048][512]  (x3 dead)

    float* feat = (float*)d_out;                 // [2048][512]
    float* out2 = feat + (size_t)NROWS * HD;     // [2048][1]

    const dim3 blk(256);

    // weight conversion + transpose (runs every call; ~30 us)
    conv_bf16_kernel<<<1024, blk, 0, stream>>>(input, inbf, 2048 * 512 / 4);
    conv_transpose_kernel<<<dim3(1024 / 32,  512 / 32), blk, 0, stream>>>(W1, W1t,  512, 1024);
    conv_transpose_kernel<<<dim3(1536 / 32, 1024 / 32), blk, 0, stream>>>(W2, W2t, 1024, 1536);
    conv_transpose_kernel<<<dim3(1536 / 32, 1536 / 32), blk, 0, stream>>>(Wh, Wht, 1536, 1536);
    conv_transpose_kernel<<<dim3(1024 / 32, 1536 / 32), blk, 0, stream>>>(W3, W3t, 1536, 1024);
    conv_transpose_kernel<<<dim3( 512 / 32, 1024 / 32), blk, 0, stream>>>(W4, W4t, 1024,  512);
    conv_transpose_kernel<<<dim3(2048 / 32,  512 / 32), blk, 0, stream>>>(T,  Tt,   512, 2048);

    // MFMA GEMM chain (bf16 in, bf16/f32 out)
    gemm_bf16_kernel<1, 0, 1, 1><<<dim3(1024 / 64, 16), blk, 0, stream>>>(inbf, W1t, b1, x1bf, nullptr, 512, 1024);
    gemm_bf16_kernel<1, 0, 1, 1><<<dim3(1536 / 64, 16), blk, 0, stream>>>(x1bf, W2t, b2, x2bf, nullptr, 1024, 1536);
    gemm_bf16_kernel<1, 0, 1, 1><<<dim3(1536 / 64, 16), blk, 0, stream>>>(x2bf, Wht, bh, x3bf, nullptr, 1536, 1536);
    gemm_bf16_kernel<1, 0, 1, 1><<<dim3(1024 / 64, 16), blk, 0, stream>>>(x3bf, W3t, b3, x4bf, nullptr, 1536, 1024);
    gemm_bf16_kernel<1, 1, 1, 1><<<dim3( 512 / 64, 16), blk, 0, stream>>>(x4bf, W4t, b4, featbf, feat, 1024, 512);
    gemm_bf16_kernel<0, 1, 0, 0><<<dim3(2048 / 64, 16), blk, 0, stream>>>(featbf, Tt, nullptr, nullptr, Ms, 512, 2048);

    // minibatch discrimination
    hipMemsetAsync(oT, 0, (size_t)NROWS * DBx * sizeof(float), stream);
    mbdisc_kernel<<<dim3(NROWS / 256, DBx, JSPLIT), blk, 0, stream>>>(Ms, oT);

    logits_kernel<<<NROWS, blk, 0, stream>>>(feat, oT, Wo, bo, out2);
}

// Round 4
// 319.743 us; speedup vs baseline: 3.6958x; 1.3820x over previous
//
#include <hip/hip_runtime.h>
#include <hip/hip_bf16.h>
#include <math.h>

#define NROWS 2048
#define HD 512
#define DBx 128
#define DCx 16

typedef __attribute__((ext_vector_type(8))) short bf16x8;
typedef __attribute__((ext_vector_type(4))) float f32x4;

__device__ inline unsigned pack2_bf16(float a, float b) {
    union { __hip_bfloat162 h; unsigned u; } cv;
    cv.h = __float22bfloat162_rn(make_float2(a, b));
    return cv.u;
}
__device__ inline unsigned short pack1_bf16(float a) {
    union { __hip_bfloat16 h; unsigned short u; } cv;
    cv.h = __float2bfloat16(a);
    return cv.u;
}

// ---------------------------------------------------------------------------
// f32 [n] -> bf16 [n] straight conversion (input activations).
// ---------------------------------------------------------------------------
__global__ __launch_bounds__(256) void conv_bf16_kernel(const float* __restrict__ in,
                                                        unsigned short* __restrict__ out,
                                                        int n4) {
    for (int idx = blockIdx.x * 256 + threadIdx.x; idx < n4; idx += gridDim.x * 256) {
        const float4 v = *reinterpret_cast<const float4*>(in + (size_t)idx * 4);
        uint2 o;
        o.x = pack2_bf16(v.x, v.y);
        o.y = pack2_bf16(v.z, v.w);
        *reinterpret_cast<uint2*>(out + (size_t)idx * 4) = o;
    }
}

// ---------------------------------------------------------------------------
// Transpose+convert: W f32 [K][M] -> Wt bf16 [M][K]. 32x32 tiles.
// ---------------------------------------------------------------------------
__global__ __launch_bounds__(256) void conv_transpose_kernel(const float* __restrict__ W,
                                                             unsigned short* __restrict__ Wt,
                                                             int K, int M) {
    __shared__ float tile[32][33];
    const int t  = threadIdx.x;
    const int tr = t >> 3;
    const int tc = t & 7;
    const int k0 = blockIdx.y * 32;
    const int m0 = blockIdx.x * 32;

    const float4 v = *reinterpret_cast<const float4*>(&W[(size_t)(k0 + tr) * M + m0 + tc * 4]);
    tile[tr][tc * 4 + 0] = v.x;
    tile[tr][tc * 4 + 1] = v.y;
    tile[tr][tc * 4 + 2] = v.z;
    tile[tr][tc * 4 + 3] = v.w;
    __syncthreads();

    const float a = tile[tc * 4 + 0][tr];
    const float b = tile[tc * 4 + 1][tr];
    const float c = tile[tc * 4 + 2][tr];
    const float d = tile[tc * 4 + 3][tr];
    uint2 o;
    o.x = pack2_bf16(a, b);
    o.y = pack2_bf16(c, d);
    *reinterpret_cast<uint2*>(&Wt[(size_t)(m0 + tr) * K + k0 + tc * 4]) = o;
}

// ---------------------------------------------------------------------------
// bf16 MFMA GEMM. A bf16 [rows][K], Bt bf16 [M][K] (pre-transposed weights).
// BM=128, BN=64, BK=64. 256 threads = 4 waves (2M x 2N), wave = 64x32 out.
// ---------------------------------------------------------------------------
template<int WRITE_BF16, int WRITE_F32, int RELU, int BIAS>
__global__ __launch_bounds__(256) void gemm_bf16_kernel(const unsigned short* __restrict__ Abf,
                                                        const unsigned short* __restrict__ Bt,
                                                        const float* __restrict__ bias,
                                                        unsigned short* __restrict__ Cbf,
                                                        float* __restrict__ Cf,
                                                        int K, int M) {
    __shared__ unsigned short As[128 * 64];
    __shared__ unsigned short Bs[64 * 64];

    const int t    = threadIdx.x;
    const int lane = t & 63;
    const int wv   = t >> 6;
    const int wm   = wv & 1;
    const int wn   = wv >> 1;
    const int row0 = blockIdx.y * 128;
    const int col0 = blockIdx.x * 64;

    const int gl_r = lane >> 3;
    const int gl_c = lane & 7;

    f32x4 acc[4][2] = {};

    for (int kt = 0; kt < K; kt += 64) {
        __syncthreads();
        #pragma unroll
        for (int q = 0; q < 4; ++q) {
            const int r = wv * 32 + q * 8 + gl_r;
            const unsigned short* src = Abf + (size_t)(row0 + r) * K + kt + 8 * (gl_c ^ (r & 7));
            __builtin_amdgcn_global_load_lds(
                (const __attribute__((address_space(1))) void*)src,
                (__attribute__((address_space(3))) void*)(As + (wv * 32 + q * 8) * 64),
                16, 0, 0);
        }
        #pragma unroll
        for (int q = 0; q < 2; ++q) {
            const int n = wv * 16 + q * 8 + gl_r;
            const unsigned short* src = Bt + (size_t)(col0 + n) * K + kt + 8 * (gl_c ^ (n & 7));
            __builtin_amdgcn_global_load_lds(
                (const __attribute__((address_space(1))) void*)src,
                (__attribute__((address_space(3))) void*)(Bs + (wv * 16 + q * 8) * 64),
                16, 0, 0);
        }
        __syncthreads();

        const int lm = lane & 15;
        const int kg = lane >> 4;
        #pragma unroll
        for (int ks = 0; ks < 2; ++ks) {
            bf16x8 af[4], bfr[2];
            #pragma unroll
            for (int fi = 0; fi < 4; ++fi) {
                const int r  = wm * 64 + fi * 16 + lm;
                const int ch = (kg + 4 * ks) ^ (r & 7);
                af[fi] = *reinterpret_cast<const bf16x8*>((const char*)As + r * 128 + ch * 16);
            }
            #pragma unroll
            for (int fj = 0; fj < 2; ++fj) {
                const int n  = wn * 32 + fj * 16 + lm;
                const int ch = (kg + 4 * ks) ^ (n & 7);
                bfr[fj] = *reinterpret_cast<const bf16x8*>((const char*)Bs + n * 128 + ch * 16);
            }
            #pragma unroll
            for (int fi = 0; fi < 4; ++fi)
                #pragma unroll
                for (int fj = 0; fj < 2; ++fj)
                    acc[fi][fj] = __builtin_amdgcn_mfma_f32_16x16x32_bf16(
                        af[fi], bfr[fj], acc[fi][fj], 0, 0, 0);
        }
    }

    const int lm = lane & 15;
    const int lq = lane >> 4;
    #pragma unroll
    for (int fj = 0; fj < 2; ++fj) {
        const int col = col0 + wn * 32 + fj * 16 + lm;
        const float bv = BIAS ? bias[col] : 0.f;
        #pragma unroll
        for (int fi = 0; fi < 4; ++fi) {
            #pragma unroll
            for (int r = 0; r < 4; ++r) {
                const int row = row0 + wm * 64 + fi * 16 + lq * 4 + r;
                float v = acc[fi][fj][r] + bv;
                if (RELU) v = fmaxf(v, 0.f);
                if (WRITE_F32)  Cf[(size_t)row * M + col] = v;
                if (WRITE_BF16) Cbf[(size_t)row * M + col] = pack1_bf16(v);
            }
        }
    }
}

// ---------------------------------------------------------------------------
// Row norms per (i,b): nrm[b][i] = 0.99 * sum_c Ms[i][b*16+c]^2  (f32 exact,
// pre-scaled by 0.99 for the gate's error margin).
// ---------------------------------------------------------------------------
__global__ __launch_bounds__(256) void norms_kernel(const float* __restrict__ Ms,
                                                    float* __restrict__ nrm) {
    const int g = blockIdx.x * 256 + threadIdx.x;   // < 2048*128
    const int i = g >> 7;
    const int b = g & 127;
    const float* p = Ms + (size_t)i * 2048 + b * 16;
    float s = 0.f;
    #pragma unroll
    for (int c = 0; c < 16; c += 4) {
        const float4 v = *reinterpret_cast<const float4*>(p + c);
        s += v.x * v.x + v.y * v.y + v.z * v.z + v.w * v.w;
    }
    nrm[(size_t)b * 2048 + i] = 0.99f * s;
}

// ---------------------------------------------------------------------------
// MFMA-gated minibatch discrimination.
// Gate: skip (i,j) iff g = 0.99(n_i+n_j) - 2*dot_bf16(m_i,m_j) >= 1450.
// Soundness (worst-case): |dot err| <= 0.008*sqrt(n_i n_j) <= 0.004(n_i+n_j)
// => skip implies true L2^2 >= 1296 => true L1 >= 36 => skipped mass
// < 2048*e^-36 ~ 5e-13. Passers (essentially j==i) recompute exact f32 L1
// and atomicAdd into outT (pre-zeroed).
// K=16 mapped to the 16x16x32 MFMA by duplicating the 16 c's into both
// k-halves (acc = 2*dot; correct under any HW k-permutation since A and B
// use the identical slot->c map).
// ---------------------------------------------------------------------------
#define JT 128
__global__ __launch_bounds__(256) void mbdisc_mfma_kernel(const float* __restrict__ Ms,
                                                          const float* __restrict__ nrm,
                                                          float* __restrict__ outT) {
    __shared__ unsigned short Bj[JT][24];   // bf16, 48B row stride (16B-aligned chunks)
    __shared__ float nj[JT];                // 0.99*n_j

    const int t    = threadIdx.x;
    const int lane = t & 63;
    const int wv   = t >> 6;
    const int b    = blockIdx.y;
    const int i0   = blockIdx.x * 64 + wv * 16;
    const int lm   = lane & 15;
    const int kg   = lane >> 4;

    // A-frag: row i0+lm, c duplicated into both k-halves via (kg&1)
    bf16x8 af;
    {
        const float* pa = Ms + (size_t)(i0 + lm) * 2048 + b * 16 + (kg & 1) * 8;
        const float4 v0 = *reinterpret_cast<const float4*>(pa);
        const float4 v1 = *reinterpret_cast<const float4*>(pa + 4);
        uint4 o;
        o.x = pack2_bf16(v0.x, v0.y); o.y = pack2_bf16(v0.z, v0.w);
        o.z = pack2_bf16(v1.x, v1.y); o.w = pack2_bf16(v1.z, v1.w);
        af = *reinterpret_cast<bf16x8*>(&o);
    }
    float nI[4];
    #pragma unroll
    for (int r = 0; r < 4; ++r)
        nI[r] = nrm[(size_t)b * 2048 + i0 + kg * 4 + r];   // already *0.99

    for (int jt = 0; jt < NROWS / JT; ++jt) {
        const int j0 = jt * JT;
        __syncthreads();
        {
            const int r = t >> 1, h = t & 1;
            const float* ps = Ms + (size_t)(j0 + r) * 2048 + b * 16 + h * 8;
            const float4 a = *reinterpret_cast<const float4*>(ps);
            const float4 c = *reinterpret_cast<const float4*>(ps + 4);
            uint4 o;
            o.x = pack2_bf16(a.x, a.y); o.y = pack2_bf16(a.z, a.w);
            o.z = pack2_bf16(c.x, c.y); o.w = pack2_bf16(c.z, c.w);
            *reinterpret_cast<uint4*>(&Bj[r][h * 8]) = o;
            if (t < JT) nj[t] = nrm[(size_t)b * 2048 + j0 + t];
        }
        __syncthreads();

        #pragma unroll
        for (int sub = 0; sub < JT / 16; ++sub) {
            const bf16x8 bf = *reinterpret_cast<const bf16x8*>(&Bj[sub * 16 + lm][(kg & 1) * 8]);
            const float njv = nj[sub * 16 + lm];
            const f32x4 zero = {0.f, 0.f, 0.f, 0.f};
            const f32x4 acc = __builtin_amdgcn_mfma_f32_16x16x32_bf16(af, bf, zero, 0, 0, 0);
            float g[4];
            #pragma unroll
            for (int r = 0; r < 4; ++r) g[r] = (nI[r] + njv) - acc[r];
            const float gmin = fminf(fminf(g[0], g[1]), fminf(g[2], g[3]));
            if (__any(gmin < 1450.f)) {
                #pragma unroll
                for (int r = 0; r < 4; ++r) {
                    if (g[r] < 1450.f) {
                        const int i = i0 + kg * 4 + r;
                        const int j = j0 + sub * 16 + lm;
                        const float* pi = Ms + (size_t)i * 2048 + b * 16;
                        const float* pj = Ms + (size_t)j * 2048 + b * 16;
                        float s = 0.f;
                        #pragma unroll
                        for (int c = 0; c < 16; c += 4) {
                            const float4 x = *reinterpret_cast<const float4*>(pi + c);
                            const float4 y = *reinterpret_cast<const float4*>(pj + c);
                            s += (fabsf(x.x - y.x) + fabsf(x.y - y.y)) +
                                 (fabsf(x.z - y.z) + fabsf(x.w - y.w));
                        }
                        atomicAdd(&outT[(size_t)i * DBx + b], __expf(-s));
                    }
                }
            }
        }
    }
}

// ---------------------------------------------------------------------------
// logits = sigmoid(concat(feature, outT) @ Wo + bo). One block per row.
// ---------------------------------------------------------------------------
__global__ __launch_bounds__(256) void logits_kernel(const float* __restrict__ feat,
                                                     const float* __restrict__ outT,
                                                     const float* __restrict__ Wo,
                                                     const float* __restrict__ bo,
                                                     float* __restrict__ out2) {
    const int row = blockIdx.x;
    const int t   = threadIdx.x;
    float p = 0.f;
    for (int k = t; k < HD + DBx; k += 256) {
        const float x = (k < HD) ? feat[(size_t)row * HD + k]
                                 : outT[(size_t)row * DBx + (k - HD)];
        p += x * Wo[k];
    }
    #pragma unroll
    for (int off = 32; off; off >>= 1) p += __shfl_down(p, off, 64);
    __shared__ float ws[4];
    if ((t & 63) == 0) ws[t >> 6] = p;
    __syncthreads();
    if (t == 0) {
        const float s = ws[0] + ws[1] + ws[2] + ws[3] + bo[0];
        out2[row] = 1.f / (1.f + __expf(-s));
    }
}

// ---------------------------------------------------------------------------
extern "C" void kernel_launch(void* const* d_in, const int* in_sizes, int n_in,
                              void* d_out, int out_size, void* d_ws, size_t ws_size,
                              hipStream_t stream) {
    const float* input = (const float*)d_in[0];
    const float* W1 = (const float*)d_in[1];
    const float* b1 = (const float*)d_in[2];
    const float* W2 = (const float*)d_in[3];
    const float* b2 = (const float*)d_in[4];
    const float* Wh = (const float*)d_in[5];
    const float* bh = (const float*)d_in[6];
    const float* W3 = (const float*)d_in[7];
    const float* b3 = (const float*)d_in[8];
    const float* W4 = (const float*)d_in[9];
    const float* b4 = (const float*)d_in[10];
    const float* Wo = (const float*)d_in[11];
    const float* bo = (const float*)d_in[12];
    const float* T  = (const float*)d_in[13];

    char* w = (char*)d_ws;
    unsigned short* inbf = (unsigned short*)w;  w += (size_t)2048 * 512 * 2;
    unsigned short* W1t  = (unsigned short*)w;  w += (size_t)1024 * 512 * 2;
    unsigned short* W2t  = (unsigned short*)w;  w += (size_t)1536 * 1024 * 2;
    unsigned short* Wht  = (unsigned short*)w;  w += (size_t)1536 * 1536 * 2;
    unsigned short* W3t  = (unsigned short*)w;  w += (size_t)1024 * 1536 * 2;
    unsigned short* W4t  = (unsigned short*)w;  w += (size_t)512 * 1024 * 2;
    unsigned short* Tt   = (unsigned short*)w;  w += (size_t)2048 * 512 * 2;
    unsigned short* slabA = (unsigned short*)w; w += (size_t)2048 * 1536 * 2;
    unsigned short* slabB = (unsigned short*)w; w += (size_t)2048 * 1536 * 2;
    float* Ms  = (float*)w;                     w += (size_t)2048 * 2048 * 4;
    float* oT  = (float*)w;                     w += (size_t)2048 * 128 * 4;
    float* nrm = (float*)w;                     w += (size_t)128 * 2048 * 4;

    unsigned short* x1bf   = slabA;
    unsigned short* x2bf   = slabB;
    unsigned short* x3bf   = slabA;
    unsigned short* x4bf   = slabB;
    unsigned short* featbf = slabA;

    float* feat = (float*)d_out;
    float* out2 = feat + (size_t)NROWS * HD;

    const dim3 blk(256);

    conv_bf16_kernel<<<1024, blk, 0, stream>>>(input, inbf, 2048 * 512 / 4);
    conv_transpose_kernel<<<dim3(1024 / 32,  512 / 32), blk, 0, stream>>>(W1, W1t,  512, 1024);
    conv_transpose_kernel<<<dim3(1536 / 32, 1024 / 32), blk, 0, stream>>>(W2, W2t, 1024, 1536);
    conv_transpose_kernel<<<dim3(1536 / 32, 1536 / 32), blk, 0, stream>>>(Wh, Wht, 1536, 1536);
    conv_transpose_kernel<<<dim3(1024 / 32, 1536 / 32), blk, 0, stream>>>(W3, W3t, 1536, 1024);
    conv_transpose_kernel<<<dim3( 512 / 32, 1024 / 32), blk, 0, stream>>>(W4, W4t, 1024,  512);
    conv_transpose_kernel<<<dim3(2048 / 32,  512 / 32), blk, 0, stream>>>(T,  Tt,   512, 2048);

    gemm_bf16_kernel<1, 0, 1, 1><<<dim3(1024 / 64, 16), blk, 0, stream>>>(inbf, W1t, b1, x1bf, nullptr, 512, 1024);
    gemm_bf16_kernel<1, 0, 1, 1><<<dim3(1536 / 64, 16), blk, 0, stream>>>(x1bf, W2t, b2, x2bf, nullptr, 1024, 1536);
    gemm_bf16_kernel<1, 0, 1, 1><<<dim3(1536 / 64, 16), blk, 0, stream>>>(x2bf, Wht, bh, x3bf, nullptr, 1536, 1536);
    gemm_bf16_kernel<1, 0, 1, 1><<<dim3(1024 / 64, 16), blk, 0, stream>>>(x3bf, W3t, b3, x4bf, nullptr, 1536, 1024);
    gemm_bf16_kernel<1, 1, 1, 1><<<dim3( 512 / 64, 16), blk, 0, stream>>>(x4bf, W4t, b4, featbf, feat, 1024, 512);
    gemm_bf16_kernel<0, 1, 0, 0><<<dim3(2048 / 64, 16), blk, 0, stream>>>(featbf, Tt, nullptr, nullptr, Ms, 512, 2048);

    norms_kernel<<<1024, blk, 0, stream>>>(Ms, nrm);
    hipMemsetAsync(oT, 0, (size_t)NROWS * DBx * sizeof(float), stream);
    mbdisc_mfma_kernel<<<dim3(NROWS / 64, DBx), blk, 0, stream>>>(Ms, nrm, oT);

    logits_kernel<<<NROWS, blk, 0, stream>>>(feat, oT, Wo, bo, out2);
}

// Round 5
// 315.550 us; speedup vs baseline: 3.7449x; 1.0133x over previous
//
#include <hip/hip_runtime.h>
#include <hip/hip_bf16.h>
#include <math.h>

#define NROWS 2048
#define HD 512
#define DBx 128

typedef __attribute__((ext_vector_type(8)))  short bf16x8;
typedef __attribute__((ext_vector_type(4)))  float f32x4;
typedef __attribute__((ext_vector_type(16))) float f32x16;

__device__ inline unsigned pack2_bf16(float a, float b) {
    union { __hip_bfloat162 h; unsigned u; } cv;
    cv.h = __float22bfloat162_rn(make_float2(a, b));
    return cv.u;
}
__device__ inline unsigned short pack1_bf16(float a) {
    union { __hip_bfloat16 h; unsigned short u; } cv;
    cv.h = __float2bfloat16(a);
    return cv.u;
}

// ---------------------------------------------------------------------------
// f32 -> bf16 straight conversion (input activations).
// ---------------------------------------------------------------------------
__global__ __launch_bounds__(256) void conv_bf16_kernel(const float* __restrict__ in,
                                                        unsigned short* __restrict__ out,
                                                        int n4) {
    for (int idx = blockIdx.x * 256 + threadIdx.x; idx < n4; idx += gridDim.x * 256) {
        const float4 v = *reinterpret_cast<const float4*>(in + (size_t)idx * 4);
        uint2 o;
        o.x = pack2_bf16(v.x, v.y);
        o.y = pack2_bf16(v.z, v.w);
        *reinterpret_cast<uint2*>(out + (size_t)idx * 4) = o;
    }
}

// ---------------------------------------------------------------------------
// All 6 weight transposes (f32 [K][M] -> bf16 [M][K]) in ONE kernel.
// Per-block routing over cumulative 32x32-tile counts.
// ---------------------------------------------------------------------------
struct TransArgs {
    const float* src[6];
    unsigned short* dst[6];
    int K[6], M[6], t0[6];
};

__global__ __launch_bounds__(256) void trans_all_kernel(TransArgs a) {
    const int id = blockIdx.x;
    int m = 0;
    #pragma unroll
    for (int q = 1; q < 6; ++q) if (id >= a.t0[q]) m = q;
    const int local = id - a.t0[m];
    const int M = a.M[m], K = a.K[m];
    const int ntm = M >> 5;
    const int mt = local % ntm;
    const int kt = local / ntm;
    const float* W = a.src[m];
    unsigned short* Wt = a.dst[m];

    __shared__ float tile[32][33];
    const int t  = threadIdx.x;
    const int tr = t >> 3;
    const int tc = t & 7;
    const int k0 = kt * 32;
    const int m0 = mt * 32;

    const float4 v = *reinterpret_cast<const float4*>(&W[(size_t)(k0 + tr) * M + m0 + tc * 4]);
    tile[tr][tc * 4 + 0] = v.x;
    tile[tr][tc * 4 + 1] = v.y;
    tile[tr][tc * 4 + 2] = v.z;
    tile[tr][tc * 4 + 3] = v.w;
    __syncthreads();

    const float x = tile[tc * 4 + 0][tr];
    const float y = tile[tc * 4 + 1][tr];
    const float z = tile[tc * 4 + 2][tr];
    const float w = tile[tc * 4 + 3][tr];
    uint2 o;
    o.x = pack2_bf16(x, y);
    o.y = pack2_bf16(z, w);
    *reinterpret_cast<uint2*>(&Wt[(size_t)(m0 + tr) * K + k0 + tc * 4]) = o;
}

// ---------------------------------------------------------------------------
// bf16 MFMA GEMM, 64x64 tile, BK=64, 4 waves (2x2), 2-phase double-buffered
// global_load_lds pipeline (stage next tile BEFORE computing current; one
// barrier per K-step so stage latency hides under ds_read+MFMA).
// A bf16 [rows][K], Bt bf16 [M][K]. XOR 16B-chunk swizzle ch^(row&7).
// MSB: additionally write bf16 C in per-b layout Msb[(col>>4)][row][col&15].
// ---------------------------------------------------------------------------
template<int WRITE_BF16, int WRITE_F32, int RELU, int BIAS, int MSB>
__global__ __launch_bounds__(256) void gemm64_kernel(const unsigned short* __restrict__ Abf,
                                                     const unsigned short* __restrict__ Bt,
                                                     const float* __restrict__ bias,
                                                     unsigned short* __restrict__ Cbf,
                                                     float* __restrict__ Cf,
                                                     int K, int M) {
    __shared__ unsigned short As[2][64 * 64];
    __shared__ unsigned short Bs[2][64 * 64];

    const int t    = threadIdx.x;
    const int lane = t & 63;
    const int wv   = t >> 6;
    const int wm   = wv & 1;
    const int wn   = wv >> 1;
    const int row0 = blockIdx.y * 64;
    const int col0 = blockIdx.x * 64;
    const int gl_r = lane >> 3;
    const int gl_c = lane & 7;

    f32x4 acc[2][2] = {};

    auto STAGE = [&](int bufi, int kt) {
        #pragma unroll
        for (int q = 0; q < 2; ++q) {
            const int r = wv * 16 + q * 8 + gl_r;
            const unsigned short* srcA = Abf + (size_t)(row0 + r) * K + kt + 8 * (gl_c ^ (r & 7));
            __builtin_amdgcn_global_load_lds(
                (const __attribute__((address_space(1))) void*)srcA,
                (__attribute__((address_space(3))) void*)(&As[bufi][(wv * 16 + q * 8) * 64]),
                16, 0, 0);
            const unsigned short* srcB = Bt + (size_t)(col0 + r) * K + kt + 8 * (gl_c ^ (r & 7));
            __builtin_amdgcn_global_load_lds(
                (const __attribute__((address_space(1))) void*)srcB,
                (__attribute__((address_space(3))) void*)(&Bs[bufi][(wv * 16 + q * 8) * 64]),
                16, 0, 0);
        }
    };

    const int nkt = K >> 6;
    STAGE(0, 0);
    __syncthreads();
    int buf = 0;
    for (int kt = 0; kt < nkt; ++kt) {
        if (kt + 1 < nkt) STAGE(buf ^ 1, (kt + 1) * 64);
        const int lm = lane & 15;
        const int kg = lane >> 4;
        #pragma unroll
        for (int ks = 0; ks < 2; ++ks) {
            bf16x8 af[2], bfr[2];
            #pragma unroll
            for (int fi = 0; fi < 2; ++fi) {
                const int r  = wm * 32 + fi * 16 + lm;
                const int ch = (kg + 4 * ks) ^ (r & 7);
                af[fi] = *reinterpret_cast<const bf16x8*>((const char*)&As[buf][0] + r * 128 + ch * 16);
            }
            #pragma unroll
            for (int fj = 0; fj < 2; ++fj) {
                const int n  = wn * 32 + fj * 16 + lm;
                const int ch = (kg + 4 * ks) ^ (n & 7);
                bfr[fj] = *reinterpret_cast<const bf16x8*>((const char*)&Bs[buf][0] + n * 128 + ch * 16);
            }
            #pragma unroll
            for (int fi = 0; fi < 2; ++fi)
                #pragma unroll
                for (int fj = 0; fj < 2; ++fj)
                    acc[fi][fj] = __builtin_amdgcn_mfma_f32_16x16x32_bf16(
                        af[fi], bfr[fj], acc[fi][fj], 0, 0, 0);
        }
        __syncthreads();
        buf ^= 1;
    }

    const int lm = lane & 15;
    const int lq = lane >> 4;
    #pragma unroll
    for (int fj = 0; fj < 2; ++fj) {
        const int col = col0 + wn * 32 + fj * 16 + lm;
        const float bv = BIAS ? bias[col] : 0.f;
        #pragma unroll
        for (int fi = 0; fi < 2; ++fi) {
            #pragma unroll
            for (int r = 0; r < 4; ++r) {
                const int row = row0 + wm * 32 + fi * 16 + lq * 4 + r;
                float v = acc[fi][fj][r] + bv;
                if (RELU) v = fmaxf(v, 0.f);
                if (WRITE_F32)  Cf[(size_t)row * M + col] = v;
                if (WRITE_BF16) {
                    if (MSB)
                        Cbf[(size_t)(col >> 4) * (NROWS * 16) + (size_t)row * 16 + (col & 15)] = pack1_bf16(v);
                    else
                        Cbf[(size_t)row * M + col] = pack1_bf16(v);
                }
            }
        }
    }
}

// ---------------------------------------------------------------------------
// Row norms (scaled 0.495) + zero outT. nrm[b][i] = 0.495 * sum_c Ms[i][b*16+c]^2
// ---------------------------------------------------------------------------
__global__ __launch_bounds__(256) void norms_kernel(const float* __restrict__ Ms,
                                                    float* __restrict__ nrm,
                                                    float* __restrict__ oT) {
    const int g = blockIdx.x * 256 + threadIdx.x;   // = i*128 + b
    const int i = g >> 7;
    const int b = g & 127;
    const float* p = Ms + (size_t)i * 2048 + b * 16;
    float s = 0.f;
    #pragma unroll
    for (int c = 0; c < 16; c += 4) {
        const float4 v = *reinterpret_cast<const float4*>(p + c);
        s += v.x * v.x + v.y * v.y + v.z * v.z + v.w * v.w;
    }
    nrm[(size_t)b * 2048 + i] = 0.495f * s;
    oT[g] = 0.f;
}

// ---------------------------------------------------------------------------
// MFMA-gated minibatch discrimination, 32x32x16 (K=16 exact, 1024 pairs/MFMA).
// acc = dot_bf16(m_i,m_j) - 0.495(n_i+n_j)  (norms folded into MFMA C-in).
// Skip iff acc <= -725  <=>  0.99(n_i+n_j) - 2 dot >= 1450 (R4-proven sound:
// skipped mass < 2048 e^-36 ~ 5e-13 for ANY input). Passers recompute exact
// f32 L1 from Ms and atomicAdd. No LDS, no barriers: frags direct from Msb
// (per-b bf16 slabs, L2-resident, coalesced 16B loads).
// ---------------------------------------------------------------------------
__global__ __launch_bounds__(256) void mbdisc32_kernel(const float* __restrict__ Ms,
                                                       const unsigned short* __restrict__ Msb,
                                                       const float* __restrict__ nrm,
                                                       float* __restrict__ outT) {
    const int t    = threadIdx.x;
    const int lane = t & 63;
    const int wv   = t >> 6;
    const int b    = blockIdx.y;
    const int i0   = blockIdx.x * 128 + wv * 32;
    const int cl   = lane & 31;
    const int hk   = lane >> 5;

    const unsigned short* Mb = Msb + (size_t)b * NROWS * 16;
    const float* nb = nrm + (size_t)b * NROWS;

    // A-frag: row i0+cl, k-slots hk*8..+8 (identical map used for B => any
    // k-permutation cancels in the dot).
    const bf16x8 af = *reinterpret_cast<const bf16x8*>(Mb + (size_t)(i0 + cl) * 16 + hk * 8);

    // -0.495*n_i for the 16 accumulator rows: i = i0 + (r&3) + 8*(r>>2) + 4*hk
    float negnI[16];
    #pragma unroll
    for (int q = 0; q < 4; ++q) {
        const float4 v = *reinterpret_cast<const float4*>(nb + i0 + 4 * hk + 8 * q);
        negnI[4 * q + 0] = -v.x; negnI[4 * q + 1] = -v.y;
        negnI[4 * q + 2] = -v.z; negnI[4 * q + 3] = -v.w;
    }

    for (int j0 = 0; j0 < NROWS; j0 += 32) {
        const float njv  = nb[j0 + cl];
        const bf16x8 bfr = *reinterpret_cast<const bf16x8*>(Mb + (size_t)(j0 + cl) * 16 + hk * 8);
        f32x16 c;
        #pragma unroll
        for (int r = 0; r < 16; ++r) c[r] = negnI[r] - njv;
        const f32x16 acc = __builtin_amdgcn_mfma_f32_32x32x16_bf16(af, bfr, c, 0, 0, 0);

        float mx[8];
        #pragma unroll
        for (int r = 0; r < 8; ++r) mx[r] = fmaxf(acc[2 * r], acc[2 * r + 1]);
        #pragma unroll
        for (int r = 0; r < 4; ++r) mx[r] = fmaxf(mx[r], mx[r + 4]);
        const float m = fmaxf(fmaxf(mx[0], mx[1]), fmaxf(mx[2], mx[3]));

        if (__any(m > -725.f)) {
            #pragma unroll
            for (int r = 0; r < 16; ++r) {
                if (acc[r] > -725.f) {
                    const int i = i0 + (r & 3) + 8 * (r >> 2) + 4 * hk;
                    const int j = j0 + cl;
                    const float* pi = Ms + (size_t)i * 2048 + b * 16;
                    const float* pj = Ms + (size_t)j * 2048 + b * 16;
                    float s = 0.f;
                    #pragma unroll
                    for (int cc = 0; cc < 16; cc += 4) {
                        const float4 x = *reinterpret_cast<const float4*>(pi + cc);
                        const float4 y = *reinterpret_cast<const float4*>(pj + cc);
                        s += (fabsf(x.x - y.x) + fabsf(x.y - y.y)) +
                             (fabsf(x.z - y.z) + fabsf(x.w - y.w));
                    }
                    atomicAdd(&outT[(size_t)i * DBx + b], __expf(-s));
                }
            }
        }
    }
}

// ---------------------------------------------------------------------------
// logits = sigmoid(concat(feature, outT) @ Wo + bo). One block per row.
// ---------------------------------------------------------------------------
__global__ __launch_bounds__(256) void logits_kernel(const float* __restrict__ feat,
                                                     const float* __restrict__ outT,
                                                     const float* __restrict__ Wo,
                                                     const float* __restrict__ bo,
                                                     float* __restrict__ out2) {
    const int row = blockIdx.x;
    const int t   = threadIdx.x;
    float p = 0.f;
    for (int k = t; k < HD + DBx; k += 256) {
        const float x = (k < HD) ? feat[(size_t)row * HD + k]
                                 : outT[(size_t)row * DBx + (k - HD)];
        p += x * Wo[k];
    }
    #pragma unroll
    for (int off = 32; off; off >>= 1) p += __shfl_down(p, off, 64);
    __shared__ float ws[4];
    if ((t & 63) == 0) ws[t >> 6] = p;
    __syncthreads();
    if (t == 0) {
        const float s = ws[0] + ws[1] + ws[2] + ws[3] + bo[0];
        out2[row] = 1.f / (1.f + __expf(-s));
    }
}

// ---------------------------------------------------------------------------
extern "C" void kernel_launch(void* const* d_in, const int* in_sizes, int n_in,
                              void* d_out, int out_size, void* d_ws, size_t ws_size,
                              hipStream_t stream) {
    const float* input = (const float*)d_in[0];
    const float* W1 = (const float*)d_in[1];
    const float* b1 = (const float*)d_in[2];
    const float* W2 = (const float*)d_in[3];
    const float* b2 = (const float*)d_in[4];
    const float* Wh = (const float*)d_in[5];
    const float* bh = (const float*)d_in[6];
    const float* W3 = (const float*)d_in[7];
    const float* b3 = (const float*)d_in[8];
    const float* W4 = (const float*)d_in[9];
    const float* b4 = (const float*)d_in[10];
    const float* Wo = (const float*)d_in[11];
    const float* bo = (const float*)d_in[12];
    const float* T  = (const float*)d_in[13];

    // workspace: 46.5 MB total (Msb aliases dead inbf/W1t/W2t/Wht region)
    unsigned short* inbf  = (unsigned short*)d_ws;                 // 2 MB
    unsigned short* W1t   = inbf  + (size_t)2048 * 512;            // 1 MB
    unsigned short* W2t   = W1t   + (size_t)1024 * 512;            // 3 MB
    unsigned short* Wht   = W2t   + (size_t)1536 * 1024;           // 4.5 MB
    unsigned short* W3t   = Wht   + (size_t)1536 * 1536;           // 3 MB
    unsigned short* W4t   = W3t   + (size_t)1024 * 1536;           // 1 MB
    unsigned short* Tt    = W4t   + (size_t)512 * 1024;            // 2 MB
    unsigned short* slabA = Tt    + (size_t)2048 * 512;            // 6 MB
    unsigned short* slabB = slabA + (size_t)2048 * 1536;           // 6 MB
    float* Ms  = (float*)(slabB + (size_t)2048 * 1536);            // 16 MB
    float* oT  = Ms + (size_t)2048 * 2048;                         // 1 MB
    float* nrm = oT + (size_t)2048 * 128;                          // 1 MB
    unsigned short* Msb = inbf;  // 8 MB, dead region by T-GEMM time

    unsigned short* x1bf   = slabA;
    unsigned short* x2bf   = slabB;
    unsigned short* x3bf   = slabA;
    unsigned short* x4bf   = slabB;
    unsigned short* featbf = slabA;

    float* feat = (float*)d_out;
    float* out2 = feat + (size_t)NROWS * HD;

    const dim3 blk(256);

    conv_bf16_kernel<<<1024, blk, 0, stream>>>(input, inbf, 2048 * 512 / 4);

    TransArgs ta;
    ta.src[0] = W1; ta.dst[0] = W1t; ta.K[0] =  512; ta.M[0] = 1024; ta.t0[0] = 0;
    ta.src[1] = W2; ta.dst[1] = W2t; ta.K[1] = 1024; ta.M[1] = 1536; ta.t0[1] = 512;
    ta.src[2] = Wh; ta.dst[2] = Wht; ta.K[2] = 1536; ta.M[2] = 1536; ta.t0[2] = 2048;
    ta.src[3] = W3; ta.dst[3] = W3t; ta.K[3] = 1536; ta.M[3] = 1024; ta.t0[3] = 4352;
    ta.src[4] = W4; ta.dst[4] = W4t; ta.K[4] = 1024; ta.M[4] =  512; ta.t0[4] = 5888;
    ta.src[5] = T;  ta.dst[5] = Tt;  ta.K[5] =  512; ta.M[5] = 2048; ta.t0[5] = 6400;
    trans_all_kernel<<<7424, blk, 0, stream>>>(ta);

    gemm64_kernel<1, 0, 1, 1, 0><<<dim3(1024 / 64, 32), blk, 0, stream>>>(inbf, W1t, b1, x1bf, nullptr, 512, 1024);
    gemm64_kernel<1, 0, 1, 1, 0><<<dim3(1536 / 64, 32), blk, 0, stream>>>(x1bf, W2t, b2, x2bf, nullptr, 1024, 1536);
    gemm64_kernel<1, 0, 1, 1, 0><<<dim3(1536 / 64, 32), blk, 0, stream>>>(x2bf, Wht, bh, x3bf, nullptr, 1536, 1536);
    gemm64_kernel<1, 0, 1, 1, 0><<<dim3(1024 / 64, 32), blk, 0, stream>>>(x3bf, W3t, b3, x4bf, nullptr, 1536, 1024);
    gemm64_kernel<1, 1, 1, 1, 0><<<dim3( 512 / 64, 32), blk, 0, stream>>>(x4bf, W4t, b4, featbf, feat, 1024, 512);
    gemm64_kernel<1, 1, 0, 0, 1><<<dim3(2048 / 64, 32), blk, 0, stream>>>(featbf, Tt, nullptr, Msb, Ms, 512, 2048);

    norms_kernel<<<1024, blk, 0, stream>>>(Ms, nrm, oT);
    mbdisc32_kernel<<<dim3(NROWS / 128, DBx), blk, 0, stream>>>(Ms, Msb, nrm, oT);

    logits_kernel<<<NROWS, blk, 0, stream>>>(feat, oT, Wo, bo, out2);
}

// Round 7
// 287.994 us; speedup vs baseline: 4.1032x; 1.0957x over previous
//
#include <hip/hip_runtime.h>
#include <hip/hip_bf16.h>
#include <math.h>

#define NROWS 2048
#define HD 512
#define DBx 128

typedef __attribute__((ext_vector_type(8)))  short bf16x8;
typedef __attribute__((ext_vector_type(4)))  float f32x4;
typedef __attribute__((ext_vector_type(16))) float f32x16;

__device__ inline unsigned pack2_bf16(float a, float b) {
    union { __hip_bfloat162 h; unsigned u; } cv;
    cv.h = __float22bfloat162_rn(make_float2(a, b));
    return cv.u;
}
__device__ inline unsigned short pack1_bf16(float a) {
    union { __hip_bfloat16 h; unsigned short u; } cv;
    cv.h = __float2bfloat16(a);
    return cv.u;
}

// ---------------------------------------------------------------------------
// f32 -> bf16 straight conversion (input activations).
// ---------------------------------------------------------------------------
__global__ __launch_bounds__(256) void conv_bf16_kernel(const float* __restrict__ in,
                                                        unsigned short* __restrict__ out,
                                                        int n4) {
    for (int idx = blockIdx.x * 256 + threadIdx.x; idx < n4; idx += gridDim.x * 256) {
        const float4 v = *reinterpret_cast<const float4*>(in + (size_t)idx * 4);
        uint2 o;
        o.x = pack2_bf16(v.x, v.y);
        o.y = pack2_bf16(v.z, v.w);
        *reinterpret_cast<uint2*>(out + (size_t)idx * 4) = o;
    }
}

// ---------------------------------------------------------------------------
// All 6 weight transposes (f32 [K][M] -> bf16 [M][K]) in ONE kernel.
// ---------------------------------------------------------------------------
struct TransArgs {
    const float* src[6];
    unsigned short* dst[6];
    int K[6], M[6], t0[6];
};

__global__ __launch_bounds__(256) void trans_all_kernel(TransArgs a) {
    const int id = blockIdx.x;
    int m = 0;
    #pragma unroll
    for (int q = 1; q < 6; ++q) if (id >= a.t0[q]) m = q;
    const int local = id - a.t0[m];
    const int M = a.M[m], K = a.K[m];
    const int ntm = M >> 5;
    const int mt = local % ntm;
    const int kt = local / ntm;
    const float* W = a.src[m];
    unsigned short* Wt = a.dst[m];

    __shared__ float tile[32][33];
    const int t  = threadIdx.x;
    const int tr = t >> 3;
    const int tc = t & 7;
    const int k0 = kt * 32;
    const int m0 = mt * 32;

    const float4 v = *reinterpret_cast<const float4*>(&W[(size_t)(k0 + tr) * M + m0 + tc * 4]);
    tile[tr][tc * 4 + 0] = v.x;
    tile[tr][tc * 4 + 1] = v.y;
    tile[tr][tc * 4 + 2] = v.z;
    tile[tr][tc * 4 + 3] = v.w;
    __syncthreads();

    const float x = tile[tc * 4 + 0][tr];
    const float y = tile[tc * 4 + 1][tr];
    const float z = tile[tc * 4 + 2][tr];
    const float w = tile[tc * 4 + 3][tr];
    uint2 o;
    o.x = pack2_bf16(x, y);
    o.y = pack2_bf16(z, w);
    *reinterpret_cast<uint2*>(&Wt[(size_t)(m0 + tr) * K + k0 + tc * 4]) = o;
}

// ---------------------------------------------------------------------------
// bf16 MFMA GEMM, 128x64 tile, BK=64, 4 waves (2Mx2N), wave = 64x32 out,
// 2-phase double-buffered global_load_lds pipeline.
// ---------------------------------------------------------------------------
template<int WRITE_BF16, int WRITE_F32, int RELU, int BIAS, int MSB>
__global__ __launch_bounds__(256) void gemm128_kernel(const unsigned short* __restrict__ Abf,
                                                      const unsigned short* __restrict__ Bt,
                                                      const float* __restrict__ bias,
                                                      unsigned short* __restrict__ Cbf,
                                                      float* __restrict__ Cf,
                                                      int K, int M) {
    __shared__ unsigned short As[2][128 * 64];   // 16 KB x2
    __shared__ unsigned short Bs[2][64 * 64];    //  8 KB x2

    const int t    = threadIdx.x;
    const int lane = t & 63;
    const int wv   = t >> 6;
    const int wm   = wv & 1;
    const int wn   = wv >> 1;
    const int row0 = blockIdx.y * 128;
    const int col0 = blockIdx.x * 64;
    const int gl_r = lane >> 3;
    const int gl_c = lane & 7;

    f32x4 acc[4][2] = {};

    auto STAGE = [&](int bufi, int kt) {
        #pragma unroll
        for (int q = 0; q < 4; ++q) {
            const int r = wv * 32 + q * 8 + gl_r;
            const unsigned short* srcA = Abf + (size_t)(row0 + r) * K + kt + 8 * (gl_c ^ (r & 7));
            __builtin_amdgcn_global_load_lds(
                (const __attribute__((address_space(1))) void*)srcA,
                (__attribute__((address_space(3))) void*)(&As[bufi][(wv * 32 + q * 8) * 64]),
                16, 0, 0);
        }
        #pragma unroll
        for (int q = 0; q < 2; ++q) {
            const int n = wv * 16 + q * 8 + gl_r;
            const unsigned short* srcB = Bt + (size_t)(col0 + n) * K + kt + 8 * (gl_c ^ (n & 7));
            __builtin_amdgcn_global_load_lds(
                (const __attribute__((address_space(1))) void*)srcB,
                (__attribute__((address_space(3))) void*)(&Bs[bufi][(wv * 16 + q * 8) * 64]),
                16, 0, 0);
        }
    };

    const int nkt = K >> 6;
    STAGE(0, 0);
    __syncthreads();
    int buf = 0;
    for (int kt = 0; kt < nkt; ++kt) {
        if (kt + 1 < nkt) STAGE(buf ^ 1, (kt + 1) * 64);
        const int lm = lane & 15;
        const int kg = lane >> 4;
        #pragma unroll
        for (int ks = 0; ks < 2; ++ks) {
            bf16x8 af[4], bfr[2];
            #pragma unroll
            for (int fi = 0; fi < 4; ++fi) {
                const int r  = wm * 64 + fi * 16 + lm;
                const int ch = (kg + 4 * ks) ^ (r & 7);
                af[fi] = *reinterpret_cast<const bf16x8*>((const char*)&As[buf][0] + r * 128 + ch * 16);
            }
            #pragma unroll
            for (int fj = 0; fj < 2; ++fj) {
                const int n  = wn * 32 + fj * 16 + lm;
                const int ch = (kg + 4 * ks) ^ (n & 7);
                bfr[fj] = *reinterpret_cast<const bf16x8*>((const char*)&Bs[buf][0] + n * 128 + ch * 16);
            }
            #pragma unroll
            for (int fi = 0; fi < 4; ++fi)
                #pragma unroll
                for (int fj = 0; fj < 2; ++fj)
                    acc[fi][fj] = __builtin_amdgcn_mfma_f32_16x16x32_bf16(
                        af[fi], bfr[fj], acc[fi][fj], 0, 0, 0);
        }
        __syncthreads();
        buf ^= 1;
    }

    const int lm = lane & 15;
    const int lq = lane >> 4;
    #pragma unroll
    for (int fj = 0; fj < 2; ++fj) {
        const int col = col0 + wn * 32 + fj * 16 + lm;
        const float bv = BIAS ? bias[col] : 0.f;
        #pragma unroll
        for (int fi = 0; fi < 4; ++fi) {
            #pragma unroll
            for (int r = 0; r < 4; ++r) {
                const int row = row0 + wm * 64 + fi * 16 + lq * 4 + r;
                float v = acc[fi][fj][r] + bv;
                if (RELU) v = fmaxf(v, 0.f);
                if (WRITE_F32)  Cf[(size_t)row * M + col] = v;
                if (WRITE_BF16) {
                    if (MSB)
                        Cbf[(size_t)(col >> 4) * (NROWS * 16) + (size_t)row * 16 + (col & 15)] = pack1_bf16(v);
                    else
                        Cbf[(size_t)row * M + col] = pack1_bf16(v);
                }
            }
        }
    }
}

// ---------------------------------------------------------------------------
// bf16 MFMA GEMM, 64x64 tile (for M=512 layer), 2-phase dbuf.
// ---------------------------------------------------------------------------
template<int WRITE_BF16, int WRITE_F32, int RELU, int BIAS>
__global__ __launch_bounds__(256) void gemm64_kernel(const unsigned short* __restrict__ Abf,
                                                     const unsigned short* __restrict__ Bt,
                                                     const float* __restrict__ bias,
                                                     unsigned short* __restrict__ Cbf,
                                                     float* __restrict__ Cf,
                                                     int K, int M) {
    __shared__ unsigned short As[2][64 * 64];
    __shared__ unsigned short Bs[2][64 * 64];

    const int t    = threadIdx.x;
    const int lane = t & 63;
    const int wv   = t >> 6;
    const int wm   = wv & 1;
    const int wn   = wv >> 1;
    const int row0 = blockIdx.y * 64;
    const int col0 = blockIdx.x * 64;
    const int gl_r = lane >> 3;
    const int gl_c = lane & 7;

    f32x4 acc[2][2] = {};

    auto STAGE = [&](int bufi, int kt) {
        #pragma unroll
        for (int q = 0; q < 2; ++q) {
            const int r = wv * 16 + q * 8 + gl_r;
            const unsigned short* srcA = Abf + (size_t)(row0 + r) * K + kt + 8 * (gl_c ^ (r & 7));
            __builtin_amdgcn_global_load_lds(
                (const __attribute__((address_space(1))) void*)srcA,
                (__attribute__((address_space(3))) void*)(&As[bufi][(wv * 16 + q * 8) * 64]),
                16, 0, 0);
            const unsigned short* srcB = Bt + (size_t)(col0 + r) * K + kt + 8 * (gl_c ^ (r & 7));
            __builtin_amdgcn_global_load_lds(
                (const __attribute__((address_space(1))) void*)srcB,
                (__attribute__((address_space(3))) void*)(&Bs[bufi][(wv * 16 + q * 8) * 64]),
                16, 0, 0);
        }
    };

    const int nkt = K >> 6;
    STAGE(0, 0);
    __syncthreads();
    int buf = 0;
    for (int kt = 0; kt < nkt; ++kt) {
        if (kt + 1 < nkt) STAGE(buf ^ 1, (kt + 1) * 64);
        const int lm = lane & 15;
        const int kg = lane >> 4;
        #pragma unroll
        for (int ks = 0; ks < 2; ++ks) {
            bf16x8 af[2], bfr[2];
            #pragma unroll
            for (int fi = 0; fi < 2; ++fi) {
                const int r  = wm * 32 + fi * 16 + lm;
                const int ch = (kg + 4 * ks) ^ (r & 7);
                af[fi] = *reinterpret_cast<const bf16x8*>((const char*)&As[buf][0] + r * 128 + ch * 16);
            }
            #pragma unroll
            for (int fj = 0; fj < 2; ++fj) {
                const int n  = wn * 32 + fj * 16 + lm;
                const int ch = (kg + 4 * ks) ^ (n & 7);
                bfr[fj] = *reinterpret_cast<const bf16x8*>((const char*)&Bs[buf][0] + n * 128 + ch * 16);
            }
            #pragma unroll
            for (int fi = 0; fi < 2; ++fi)
                #pragma unroll
                for (int fj = 0; fj < 2; ++fj)
                    acc[fi][fj] = __builtin_amdgcn_mfma_f32_16x16x32_bf16(
                        af[fi], bfr[fj], acc[fi][fj], 0, 0, 0);
        }
        __syncthreads();
        buf ^= 1;
    }

    const int lm = lane & 15;
    const int lq = lane >> 4;
    #pragma unroll
    for (int fj = 0; fj < 2; ++fj) {
        const int col = col0 + wn * 32 + fj * 16 + lm;
        const float bv = BIAS ? bias[col] : 0.f;
        #pragma unroll
        for (int fi = 0; fi < 2; ++fi) {
            #pragma unroll
            for (int r = 0; r < 4; ++r) {
                const int row = row0 + wm * 32 + fi * 16 + lq * 4 + r;
                float v = acc[fi][fj][r] + bv;
                if (RELU) v = fmaxf(v, 0.f);
                if (WRITE_F32)  Cf[(size_t)row * M + col] = v;
                if (WRITE_BF16) Cbf[(size_t)row * M + col] = pack1_bf16(v);
            }
        }
    }
}

// ---------------------------------------------------------------------------
// Row norms (scaled 0.495) + zero outT.
// ---------------------------------------------------------------------------
__global__ __launch_bounds__(256) void norms_kernel(const float* __restrict__ Ms,
                                                    float* __restrict__ nrm,
                                                    float* __restrict__ oT) {
    const int g = blockIdx.x * 256 + threadIdx.x;
    const int i = g >> 7;
    const int b = g & 127;
    const float* p = Ms + (size_t)i * 2048 + b * 16;
    float s = 0.f;
    #pragma unroll
    for (int c = 0; c < 16; c += 4) {
        const float4 v = *reinterpret_cast<const float4*>(p + c);
        s += v.x * v.x + v.y * v.y + v.z * v.z + v.w * v.w;
    }
    nrm[(size_t)b * 2048 + i] = 0.495f * s;
    oT[g] = 0.f;
}

// ---------------------------------------------------------------------------
// MFMA-gated minibatch discrimination v3: LDS-resident per-b slab.
// Block = 512 thr (8 waves), grid (8,128). Stage Msb slab (64KB, layout
// [hk][j][16B] => stride-1 conflict-free ds_read_b128) + nrm (8KB) via
// async global_load_lds once; then a BARRIER-FREE j-loop: per 32-j tile
// 1 MFMA 32x32x16 covers 1024 pairs. Gate folded so pass iff acc[r] > 0
// (c[r] = (725 - nrm_i) - nrm_j; same R4-proven sound gate: skipped mass
// < 2048 e^-36 for ANY input). Passers recompute exact f32 L1 from Ms.
// ---------------------------------------------------------------------------
__global__ __launch_bounds__(512) void mbdisc32_kernel(const float* __restrict__ Ms,
                                                       const unsigned short* __restrict__ Msb,
                                                       const float* __restrict__ nrm,
                                                       float* __restrict__ outT) {
    extern __shared__ char smem[];                       // 64KB Msb + 8KB nrm
    float* Nlds = (float*)(smem + 65536);

    const int t    = threadIdx.x;
    const int lane = t & 63;
    const int w    = t >> 6;                             // 0..7
    const int b    = blockIdx.y;
    const int i0   = blockIdx.x * 256 + w * 32;
    const int cl   = lane & 31;
    const int hk   = lane >> 5;

    const unsigned short* Mb = Msb + (size_t)b * NROWS * 16;
    const float* nb = nrm + (size_t)b * NROWS;

    // per-row thresholds: pI[r] = 725 - 0.495*n_i, i = i0 + (r&3)+8(r>>2)+4hk
    float pI[16];
    #pragma unroll
    for (int q = 0; q < 4; ++q) {
        const float4 v = *reinterpret_cast<const float4*>(nb + i0 + 4 * hk + 8 * q);
        pI[4 * q + 0] = 725.f - v.x; pI[4 * q + 1] = 725.f - v.y;
        pI[4 * q + 2] = 725.f - v.z; pI[4 * q + 3] = 725.f - v.w;
    }
    // A-frag from global (L2), issued before staging barrier
    const bf16x8 af = *reinterpret_cast<const bf16x8*>(Mb + (size_t)(i0 + cl) * 16 + hk * 8);

    // stage slab: slot s (16B) = h*2048 + j  ->  lds byte s*16
    #pragma unroll
    for (int q = 0; q < 8; ++q) {
        const int slot = q * 512 + t;
        const int h = slot >> 11, j = slot & 2047;
        const unsigned short* src = Mb + j * 16 + h * 8;
        __builtin_amdgcn_global_load_lds(
            (const __attribute__((address_space(1))) void*)src,
            (__attribute__((address_space(3))) void*)(smem + (size_t)(q * 512 + w * 64) * 16),
            16, 0, 0);
    }
    {   // stage nrm: 2048 f32 = 512 x 16B
        const float* src = nb + t * 4;
        __builtin_amdgcn_global_load_lds(
            (const __attribute__((address_space(1))) void*)src,
            (__attribute__((address_space(3))) void*)(smem + 65536 + (size_t)(w * 64) * 16),
            16, 0, 0);
    }
    __syncthreads();

    const char* mrow = smem + hk * 32768;
    #pragma unroll 4
    for (int j0 = 0; j0 < NROWS; j0 += 32) {
        const float njv  = Nlds[j0 + cl];
        const bf16x8 bfr = *reinterpret_cast<const bf16x8*>(mrow + (size_t)(j0 + cl) * 16);
        f32x16 c;
        #pragma unroll
        for (int r = 0; r < 16; ++r) c[r] = pI[r] - njv;
        const f32x16 acc = __builtin_amdgcn_mfma_f32_32x32x16_bf16(af, bfr, c, 0, 0, 0);

        // max via fmax tree
        const float m0 = fmaxf(fmaxf(acc[0],  acc[1]),  acc[2]);
        const float m1 = fmaxf(fmaxf(acc[3],  acc[4]),  acc[5]);
        const float m2 = fmaxf(fmaxf(acc[6],  acc[7]),  acc[8]);
        const float m3 = fmaxf(fmaxf(acc[9],  acc[10]), acc[11]);
        const float m4 = fmaxf(fmaxf(acc[12], acc[13]), acc[14]);
        const float m5 = fmaxf(fmaxf(m0, m1), acc[15]);
        const float m6 = fmaxf(fmaxf(m2, m3), m4);
        const float mx = fmaxf(m5, m6);

        if (__any(mx > 0.f)) {
            #pragma unroll
            for (int r = 0; r < 16; ++r) {
                if (acc[r] > 0.f) {
                    const int i = i0 + (r & 3) + 8 * (r >> 2) + 4 * hk;
                    const int j = j0 + cl;
                    const float* pi = Ms + (size_t)i * 2048 + b * 16;
                    const float* pj = Ms + (size_t)j * 2048 + b * 16;
                    float s = 0.f;
                    #pragma unroll
                    for (int cc = 0; cc < 16; cc += 4) {
                        const float4 x = *reinterpret_cast<const float4*>(pi + cc);
                        const float4 y = *reinterpret_cast<const float4*>(pj + cc);
                        s += (fabsf(x.x - y.x) + fabsf(x.y - y.y)) +
                             (fabsf(x.z - y.z) + fabsf(x.w - y.w));
                    }
                    atomicAdd(&outT[(size_t)i * DBx + b], __expf(-s));
                }
            }
        }
    }
}

// ---------------------------------------------------------------------------
// logits = sigmoid(concat(feature, outT) @ Wo + bo). One block per row.
// ---------------------------------------------------------------------------
__global__ __launch_bounds__(256) void logits_kernel(const float* __restrict__ feat,
                                                     const float* __restrict__ outT,
                                                     const float* __restrict__ Wo,
                                                     const float* __restrict__ bo,
                                                     float* __restrict__ out2) {
    const int row = blockIdx.x;
    const int t   = threadIdx.x;
    float p = 0.f;
    for (int k = t; k < HD + DBx; k += 256) {
        const float x = (k < HD) ? feat[(size_t)row * HD + k]
                                 : outT[(size_t)row * DBx + (k - HD)];
        p += x * Wo[k];
    }
    #pragma unroll
    for (int off = 32; off; off >>= 1) p += __shfl_down(p, off, 64);
    __shared__ float ws[4];
    if ((t & 63) == 0) ws[t >> 6] = p;
    __syncthreads();
    if (t == 0) {
        const float s = ws[0] + ws[1] + ws[2] + ws[3] + bo[0];
        out2[row] = 1.f / (1.f + __expf(-s));
    }
}

// ---------------------------------------------------------------------------
extern "C" void kernel_launch(void* const* d_in, const int* in_sizes, int n_in,
                              void* d_out, int out_size, void* d_ws, size_t ws_size,
                              hipStream_t stream) {
    const float* input = (const float*)d_in[0];
    const float* W1 = (const float*)d_in[1];
    const float* b1 = (const float*)d_in[2];
    const float* W2 = (const float*)d_in[3];
    const float* b2 = (const float*)d_in[4];
    const float* Wh = (const float*)d_in[5];
    const float* bh = (const float*)d_in[6];
    const float* W3 = (const float*)d_in[7];
    const float* b3 = (const float*)d_in[8];
    const float* W4 = (const float*)d_in[9];
    const float* b4 = (const float*)d_in[10];
    const float* Wo = (const float*)d_in[11];
    const float* bo = (const float*)d_in[12];
    const float* T  = (const float*)d_in[13];

    unsigned short* inbf  = (unsigned short*)d_ws;                 // 2 MB
    unsigned short* W1t   = inbf  + (size_t)2048 * 512;            // 1 MB
    unsigned short* W2t   = W1t   + (size_t)1024 * 512;            // 3 MB
    unsigned short* Wht   = W2t   + (size_t)1536 * 1024;           // 4.5 MB
    unsigned short* W3t   = Wht   + (size_t)1536 * 1536;           // 3 MB
    unsigned short* W4t   = W3t   + (size_t)1024 * 1536;           // 1 MB
    unsigned short* Tt    = W4t   + (size_t)512 * 1024;            // 2 MB
    unsigned short* slabA = Tt    + (size_t)2048 * 512;            // 6 MB
    unsigned short* slabB = slabA + (size_t)2048 * 1536;           // 6 MB
    float* Ms  = (float*)(slabB + (size_t)2048 * 1536);            // 16 MB
    float* oT  = Ms + (size_t)2048 * 2048;                         // 1 MB
    float* nrm = oT + (size_t)2048 * 128;                          // 1 MB
    unsigned short* Msb = inbf;  // 8 MB, region dead by T-GEMM time

    unsigned short* x1bf   = slabA;
    unsigned short* x2bf   = slabB;
    unsigned short* x3bf   = slabA;
    unsigned short* x4bf   = slabB;
    unsigned short* featbf = slabA;

    float* feat = (float*)d_out;
    float* out2 = feat + (size_t)NROWS * HD;

    const dim3 blk(256);

    conv_bf16_kernel<<<1024, blk, 0, stream>>>(input, inbf, 2048 * 512 / 4);

    TransArgs ta;
    ta.src[0] = W1; ta.dst[0] = W1t; ta.K[0] =  512; ta.M[0] = 1024; ta.t0[0] = 0;
    ta.src[1] = W2; ta.dst[1] = W2t; ta.K[1] = 1024; ta.M[1] = 1536; ta.t0[1] = 512;
    ta.src[2] = Wh; ta.dst[2] = Wht; ta.K[2] = 1536; ta.M[2] = 1536; ta.t0[2] = 2048;
    ta.src[3] = W3; ta.dst[3] = W3t; ta.K[3] = 1536; ta.M[3] = 1024; ta.t0[3] = 4352;
    ta.src[4] = W4; ta.dst[4] = W4t; ta.K[4] = 1024; ta.M[4] =  512; ta.t0[4] = 5888;
    ta.src[5] = T;  ta.dst[5] = Tt;  ta.K[5] =  512; ta.M[5] = 2048; ta.t0[5] = 6400;
    trans_all_kernel<<<7424, blk, 0, stream>>>(ta);

    gemm128_kernel<1, 0, 1, 1, 0><<<dim3(1024 / 64, 16), blk, 0, stream>>>(inbf, W1t, b1, x1bf, nullptr, 512, 1024);
    gemm128_kernel<1, 0, 1, 1, 0><<<dim3(1536 / 64, 16), blk, 0, stream>>>(x1bf, W2t, b2, x2bf, nullptr, 1024, 1536);
    gemm128_kernel<1, 0, 1, 1, 0><<<dim3(1536 / 64, 16), blk, 0, stream>>>(x2bf, Wht, bh, x3bf, nullptr, 1536, 1536);
    gemm128_kernel<1, 0, 1, 1, 0><<<dim3(1024 / 64, 16), blk, 0, stream>>>(x3bf, W3t, b3, x4bf, nullptr, 1536, 1024);
    gemm64_kernel <1, 1, 1, 1>   <<<dim3( 512 / 64, 32), blk, 0, stream>>>(x4bf, W4t, b4, featbf, feat, 1024, 512);
    gemm128_kernel<1, 1, 0, 0, 1><<<dim3(2048 / 64, 16), blk, 0, stream>>>(featbf, Tt, nullptr, Msb, Ms, 512, 2048);

    norms_kernel<<<1024, blk, 0, stream>>>(Ms, nrm, oT);
    mbdisc32_kernel<<<dim3(NROWS / 256, DBx), dim3(512), 73728, stream>>>(Ms, Msb, nrm, oT);

    logits_kernel<<<NROWS, blk, 0, stream>>>(feat, oT, Wo, bo, out2);
}

// Round 9
// 270.291 us; speedup vs baseline: 4.3719x; 1.0655x over previous
//
#include <hip/hip_runtime.h>
#include <hip/hip_bf16.h>
#include <math.h>

#define NROWS 2048
#define HD 512
#define DBx 128

typedef __attribute__((ext_vector_type(8)))  short bf16x8;
typedef __attribute__((ext_vector_type(4)))  float f32x4;
typedef __attribute__((ext_vector_type(16))) float f32x16;

__device__ inline unsigned pack2_bf16(float a, float b) {
    union { __hip_bfloat162 h; unsigned u; } cv;
    cv.h = __float22bfloat162_rn(make_float2(a, b));
    return cv.u;
}
__device__ inline unsigned short pack1_bf16(float a) {
    union { __hip_bfloat16 h; unsigned short u; } cv;
    cv.h = __float2bfloat16(a);
    return cv.u;
}

// ---------------------------------------------------------------------------
// f32 -> bf16 straight conversion (input activations).
// ---------------------------------------------------------------------------
__global__ __launch_bounds__(256) void conv_bf16_kernel(const float* __restrict__ in,
                                                        unsigned short* __restrict__ out,
                                                        int n4) {
    for (int idx = blockIdx.x * 256 + threadIdx.x; idx < n4; idx += gridDim.x * 256) {
        const float4 v = *reinterpret_cast<const float4*>(in + (size_t)idx * 4);
        uint2 o;
        o.x = pack2_bf16(v.x, v.y);
        o.y = pack2_bf16(v.z, v.w);
        *reinterpret_cast<uint2*>(out + (size_t)idx * 4) = o;
    }
}

// ---------------------------------------------------------------------------
// All 6 weight transposes (f32 [K][M] -> bf16 [M][K]) in ONE kernel.
// ---------------------------------------------------------------------------
struct TransArgs {
    const float* src[6];
    unsigned short* dst[6];
    int K[6], M[6], t0[6];
};

__global__ __launch_bounds__(256) void trans_all_kernel(TransArgs a) {
    const int id = blockIdx.x;
    int m = 0;
    #pragma unroll
    for (int q = 1; q < 6; ++q) if (id >= a.t0[q]) m = q;
    const int local = id - a.t0[m];
    const int M = a.M[m], K = a.K[m];
    const int ntm = M >> 5;
    const int mt = local % ntm;
    const int kt = local / ntm;
    const float* W = a.src[m];
    unsigned short* Wt = a.dst[m];

    __shared__ float tile[32][33];
    const int t  = threadIdx.x;
    const int tr = t >> 3;
    const int tc = t & 7;
    const int k0 = kt * 32;
    const int m0 = mt * 32;

    const float4 v = *reinterpret_cast<const float4*>(&W[(size_t)(k0 + tr) * M + m0 + tc * 4]);
    tile[tr][tc * 4 + 0] = v.x;
    tile[tr][tc * 4 + 1] = v.y;
    tile[tr][tc * 4 + 2] = v.z;
    tile[tr][tc * 4 + 3] = v.w;
    __syncthreads();

    const float x = tile[tc * 4 + 0][tr];
    const float y = tile[tc * 4 + 1][tr];
    const float z = tile[tc * 4 + 2][tr];
    const float w = tile[tc * 4 + 3][tr];
    uint2 o;
    o.x = pack2_bf16(x, y);
    o.y = pack2_bf16(z, w);
    *reinterpret_cast<uint2*>(&Wt[(size_t)(m0 + tr) * K + k0 + tc * 4]) = o;
}

// ---------------------------------------------------------------------------
// bf16 MFMA GEMM, 128x64 tile, BK=64, 4 waves (2Mx2N), wave = 64x32 out,
// 2-phase double-buffered global_load_lds pipeline.
// ---------------------------------------------------------------------------
template<int WRITE_BF16, int WRITE_F32, int RELU, int BIAS, int MSB>
__global__ __launch_bounds__(256) void gemm128_kernel(const unsigned short* __restrict__ Abf,
                                                      const unsigned short* __restrict__ Bt,
                                                      const float* __restrict__ bias,
                                                      unsigned short* __restrict__ Cbf,
                                                      float* __restrict__ Cf,
                                                      int K, int M) {
    __shared__ unsigned short As[2][128 * 64];   // 16 KB x2
    __shared__ unsigned short Bs[2][64 * 64];    //  8 KB x2

    const int t    = threadIdx.x;
    const int lane = t & 63;
    const int wv   = t >> 6;
    const int wm   = wv & 1;
    const int wn   = wv >> 1;
    const int row0 = blockIdx.y * 128;
    const int col0 = blockIdx.x * 64;
    const int gl_r = lane >> 3;
    const int gl_c = lane & 7;

    f32x4 acc[4][2] = {};

    auto STAGE = [&](int bufi, int kt) {
        #pragma unroll
        for (int q = 0; q < 4; ++q) {
            const int r = wv * 32 + q * 8 + gl_r;
            const unsigned short* srcA = Abf + (size_t)(row0 + r) * K + kt + 8 * (gl_c ^ (r & 7));
            __builtin_amdgcn_global_load_lds(
                (const __attribute__((address_space(1))) void*)srcA,
                (__attribute__((address_space(3))) void*)(&As[bufi][(wv * 32 + q * 8) * 64]),
                16, 0, 0);
        }
        #pragma unroll
        for (int q = 0; q < 2; ++q) {
            const int n = wv * 16 + q * 8 + gl_r;
            const unsigned short* srcB = Bt + (size_t)(col0 + n) * K + kt + 8 * (gl_c ^ (n & 7));
            __builtin_amdgcn_global_load_lds(
                (const __attribute__((address_space(1))) void*)srcB,
                (__attribute__((address_space(3))) void*)(&Bs[bufi][(wv * 16 + q * 8) * 64]),
                16, 0, 0);
        }
    };

    const int nkt = K >> 6;
    STAGE(0, 0);
    __syncthreads();
    int buf = 0;
    for (int kt = 0; kt < nkt; ++kt) {
        if (kt + 1 < nkt) STAGE(buf ^ 1, (kt + 1) * 64);
        const int lm = lane & 15;
        const int kg = lane >> 4;
        #pragma unroll
        for (int ks = 0; ks < 2; ++ks) {
            bf16x8 af[4], bfr[2];
            #pragma unroll
            for (int fi = 0; fi < 4; ++fi) {
                const int r  = wm * 64 + fi * 16 + lm;
                const int ch = (kg + 4 * ks) ^ (r & 7);
                af[fi] = *reinterpret_cast<const bf16x8*>((const char*)&As[buf][0] + r * 128 + ch * 16);
            }
            #pragma unroll
            for (int fj = 0; fj < 2; ++fj) {
                const int n  = wn * 32 + fj * 16 + lm;
                const int ch = (kg + 4 * ks) ^ (n & 7);
                bfr[fj] = *reinterpret_cast<const bf16x8*>((const char*)&Bs[buf][0] + n * 128 + ch * 16);
            }
            #pragma unroll
            for (int fi = 0; fi < 4; ++fi)
                #pragma unroll
                for (int fj = 0; fj < 2; ++fj)
                    acc[fi][fj] = __builtin_amdgcn_mfma_f32_16x16x32_bf16(
                        af[fi], bfr[fj], acc[fi][fj], 0, 0, 0);
        }
        __syncthreads();
        buf ^= 1;
    }

    const int lm = lane & 15;
    const int lq = lane >> 4;
    #pragma unroll
    for (int fj = 0; fj < 2; ++fj) {
        const int col = col0 + wn * 32 + fj * 16 + lm;
        const float bv = BIAS ? bias[col] : 0.f;
        #pragma unroll
        for (int fi = 0; fi < 4; ++fi) {
            #pragma unroll
            for (int r = 0; r < 4; ++r) {
                const int row = row0 + wm * 64 + fi * 16 + lq * 4 + r;
                float v = acc[fi][fj][r] + bv;
                if (RELU) v = fmaxf(v, 0.f);
                if (WRITE_F32)  Cf[(size_t)row * M + col] = v;
                if (WRITE_BF16) {
                    if (MSB)
                        Cbf[(size_t)(col >> 4) * (NROWS * 16) + (size_t)row * 16 + (col & 15)] = pack1_bf16(v);
                    else
                        Cbf[(size_t)row * M + col] = pack1_bf16(v);
                }
            }
        }
    }
}

// ---------------------------------------------------------------------------
// bf16 MFMA GEMM, 64x64 tile (for M=512 layer), 2-phase dbuf.
// ---------------------------------------------------------------------------
template<int WRITE_BF16, int WRITE_F32, int RELU, int BIAS>
__global__ __launch_bounds__(256) void gemm64_kernel(const unsigned short* __restrict__ Abf,
                                                     const unsigned short* __restrict__ Bt,
                                                     const float* __restrict__ bias,
                                                     unsigned short* __restrict__ Cbf,
                                                     float* __restrict__ Cf,
                                                     int K, int M) {
    __shared__ unsigned short As[2][64 * 64];
    __shared__ unsigned short Bs[2][64 * 64];

    const int t    = threadIdx.x;
    const int lane = t & 63;
    const int wv   = t >> 6;
    const int wm   = wv & 1;
    const int wn   = wv >> 1;
    const int row0 = blockIdx.y * 64;
    const int col0 = blockIdx.x * 64;
    const int gl_r = lane >> 3;
    const int gl_c = lane & 7;

    f32x4 acc[2][2] = {};

    auto STAGE = [&](int bufi, int kt) {
        #pragma unroll
        for (int q = 0; q < 2; ++q) {
            const int r = wv * 16 + q * 8 + gl_r;
            const unsigned short* srcA = Abf + (size_t)(row0 + r) * K + kt + 8 * (gl_c ^ (r & 7));
            __builtin_amdgcn_global_load_lds(
                (const __attribute__((address_space(1))) void*)srcA,
                (__attribute__((address_space(3))) void*)(&As[bufi][(wv * 16 + q * 8) * 64]),
                16, 0, 0);
            const unsigned short* srcB = Bt + (size_t)(col0 + r) * K + kt + 8 * (gl_c ^ (r & 7));
            __builtin_amdgcn_global_load_lds(
                (const __attribute__((address_space(1))) void*)srcB,
                (__attribute__((address_space(3))) void*)(&Bs[bufi][(wv * 16 + q * 8) * 64]),
                16, 0, 0);
        }
    };

    const int nkt = K >> 6;
    STAGE(0, 0);
    __syncthreads();
    int buf = 0;
    for (int kt = 0; kt < nkt; ++kt) {
        if (kt + 1 < nkt) STAGE(buf ^ 1, (kt + 1) * 64);
        const int lm = lane & 15;
        const int kg = lane >> 4;
        #pragma unroll
        for (int ks = 0; ks < 2; ++ks) {
            bf16x8 af[2], bfr[2];
            #pragma unroll
            for (int fi = 0; fi < 2; ++fi) {
                const int r  = wm * 32 + fi * 16 + lm;
                const int ch = (kg + 4 * ks) ^ (r & 7);
                af[fi] = *reinterpret_cast<const bf16x8*>((const char*)&As[buf][0] + r * 128 + ch * 16);
            }
            #pragma unroll
            for (int fj = 0; fj < 2; ++fj) {
                const int n  = wn * 32 + fj * 16 + lm;
                const int ch = (kg + 4 * ks) ^ (n & 7);
                bfr[fj] = *reinterpret_cast<const bf16x8*>((const char*)&Bs[buf][0] + n * 128 + ch * 16);
            }
            #pragma unroll
            for (int fi = 0; fi < 2; ++fi)
                #pragma unroll
                for (int fj = 0; fj < 2; ++fj)
                    acc[fi][fj] = __builtin_amdgcn_mfma_f32_16x16x32_bf16(
                        af[fi], bfr[fj], acc[fi][fj], 0, 0, 0);
        }
        __syncthreads();
        buf ^= 1;
    }

    const int lm = lane & 15;
    const int lq = lane >> 4;
    #pragma unroll
    for (int fj = 0; fj < 2; ++fj) {
        const int col = col0 + wn * 32 + fj * 16 + lm;
        const float bv = BIAS ? bias[col] : 0.f;
        #pragma unroll
        for (int fi = 0; fi < 2; ++fi) {
            #pragma unroll
            for (int r = 0; r < 4; ++r) {
                const int row = row0 + wm * 32 + fi * 16 + lq * 4 + r;
                float v = acc[fi][fj][r] + bv;
                if (RELU) v = fmaxf(v, 0.f);
                if (WRITE_F32)  Cf[(size_t)row * M + col] = v;
                if (WRITE_BF16) Cbf[(size_t)row * M + col] = pack1_bf16(v);
            }
        }
    }
}

// ---------------------------------------------------------------------------
// Row norms (scaled 0.495) + zero outT.
// ---------------------------------------------------------------------------
__global__ __launch_bounds__(256) void norms_kernel(const float* __restrict__ Ms,
                                                    float* __restrict__ nrm,
                                                    float* __restrict__ oT) {
    const int g = blockIdx.x * 256 + threadIdx.x;
    const int i = g >> 7;
    const int b = g & 127;
    const float* p = Ms + (size_t)i * 2048 + b * 16;
    float s = 0.f;
    #pragma unroll
    for (int c = 0; c < 16; c += 4) {
        const float4 v = *reinterpret_cast<const float4*>(p + c);
        s += v.x * v.x + v.y * v.y + v.z * v.z + v.w * v.w;
    }
    nrm[(size_t)b * 2048 + i] = 0.495f * s;
    oT[g] = 0.f;
}

// ---------------------------------------------------------------------------
// MFMA-gated minibatch discrimination v4.
// Grid (2,128), 512 thr. Stage per-b slab (64KB, [hk][j][16B]) + nrm (8KB)
// ONCE per block; each wave covers 4 i-chunks of 32 rows (A-frag + C-in
// re-read from LDS per chunk). MFMA C-in carries the loop-invariant part:
// cI[r] = 725 - 0.495 n_i  =>  acc = dot + 725 - 0.495 n_i; pass iff
// acc[r] > 0.495 n_j. Algebraically identical to the R4-proven gate
// (skip <=> 0.99(n_i+n_j) - 2 dot >= 1450; skipped mass < 2048 e^-36).
// Per j-tile: 2 ds_reads + 1 MFMA (1024 pairs) + fmax tree + 1 cmp.
// ---------------------------------------------------------------------------
__global__ __launch_bounds__(512) void mbdisc32_kernel(const float* __restrict__ Ms,
                                                       const unsigned short* __restrict__ Msb,
                                                       const float* __restrict__ nrm,
                                                       float* __restrict__ outT) {
    extern __shared__ char smem[];                       // 64KB slab + 8KB nrm
    float* Nlds = (float*)(smem + 65536);

    const int t    = threadIdx.x;
    const int lane = t & 63;
    const int w    = t >> 6;                             // 0..7
    const int b    = blockIdx.y;
    const int cl   = lane & 31;
    const int hk   = lane >> 5;

    const unsigned short* Mb = Msb + (size_t)b * NROWS * 16;
    const float* nb = nrm + (size_t)b * NROWS;

    // stage slab: slot s (16B) = h*2048 + j -> lds byte s*16
    #pragma unroll
    for (int q = 0; q < 8; ++q) {
        const int slot = q * 512 + t;
        const int h = slot >> 11, j = slot & 2047;
        const unsigned short* src = Mb + j * 16 + h * 8;
        __builtin_amdgcn_global_load_lds(
            (const __attribute__((address_space(1))) void*)src,
            (__attribute__((address_space(3))) void*)(smem + (size_t)(q * 512 + w * 64) * 16),
            16, 0, 0);
    }
    {   // stage nrm: 2048 f32 = 512 x 16B
        const float* src = nb + t * 4;
        __builtin_amdgcn_global_load_lds(
            (const __attribute__((address_space(1))) void*)src,
            (__attribute__((address_space(3))) void*)(smem + 65536 + (size_t)(w * 64) * 16),
            16, 0, 0);
    }
    __syncthreads();

    const char* mrow = smem + hk * 32768;

    #pragma unroll
    for (int ic = 0; ic < 4; ++ic) {
        const int i0 = blockIdx.x * 1024 + w * 128 + ic * 32;

        // A-frag + C-in from LDS (loop-invariant over j)
        const bf16x8 af = *reinterpret_cast<const bf16x8*>(mrow + (size_t)(i0 + cl) * 16);
        f32x16 cI;
        #pragma unroll
        for (int q = 0; q < 4; ++q) {
            const f32x4 v = *reinterpret_cast<const f32x4*>(Nlds + i0 + 4 * hk + 8 * q);
            cI[4 * q + 0] = 725.f - v[0]; cI[4 * q + 1] = 725.f - v[1];
            cI[4 * q + 2] = 725.f - v[2]; cI[4 * q + 3] = 725.f - v[3];
        }

        #pragma unroll 4
        for (int j0 = 0; j0 < NROWS; j0 += 32) {
            const float njv  = Nlds[j0 + cl];
            const bf16x8 bfr = *reinterpret_cast<const bf16x8*>(mrow + (size_t)(j0 + cl) * 16);
            const f32x16 acc = __builtin_amdgcn_mfma_f32_32x32x16_bf16(af, bfr, cI, 0, 0, 0);

            const float m0 = fmaxf(fmaxf(acc[0],  acc[1]),  acc[2]);
            const float m1 = fmaxf(fmaxf(acc[3],  acc[4]),  acc[5]);
            const float m2 = fmaxf(fmaxf(acc[6],  acc[7]),  acc[8]);
            const float m3 = fmaxf(fmaxf(acc[9],  acc[10]), acc[11]);
            const float m4 = fmaxf(fmaxf(acc[12], acc[13]), acc[14]);
            const float m5 = fmaxf(fmaxf(m0, m1), acc[15]);
            const float m6 = fmaxf(fmaxf(m2, m3), m4);
            const float mx = fmaxf(m5, m6);

            if (__any(mx > njv)) {
                #pragma unroll
                for (int r = 0; r < 16; ++r) {
                    if (acc[r] > njv) {
                        const int i = i0 + (r & 3) + 8 * (r >> 2) + 4 * hk;
                        const int j = j0 + cl;
                        const float* pi = Ms + (size_t)i * 2048 + b * 16;
                        const float* pj = Ms + (size_t)j * 2048 + b * 16;
                        float s = 0.f;
                        #pragma unroll
                        for (int cc = 0; cc < 16; cc += 4) {
                            const float4 x = *reinterpret_cast<const float4*>(pi + cc);
                            const float4 y = *reinterpret_cast<const float4*>(pj + cc);
                            s += (fabsf(x.x - y.x) + fabsf(x.y - y.y)) +
                                 (fabsf(x.z - y.z) + fabsf(x.w - y.w));
                        }
                        atomicAdd(&outT[(size_t)i * DBx + b], __expf(-s));
                    }
                }
            }
        }
    }
}

// ---------------------------------------------------------------------------
// logits = sigmoid(concat(feature, outT) @ Wo + bo). One block per row.
// ---------------------------------------------------------------------------
__global__ __launch_bounds__(256) void logits_kernel(const float* __restrict__ feat,
                                                     const float* __restrict__ outT,
                                                     const float* __restrict__ Wo,
                                                     const float* __restrict__ bo,
                                                     float* __restrict__ out2) {
    const int row = blockIdx.x;
    const int t   = threadIdx.x;
    float p = 0.f;
    for (int k = t; k < HD + DBx; k += 256) {
        const float x = (k < HD) ? feat[(size_t)row * HD + k]
                                 : outT[(size_t)row * DBx + (k - HD)];
        p += x * Wo[k];
    }
    #pragma unroll
    for (int off = 32; off; off >>= 1) p += __shfl_down(p, off, 64);
    __shared__ float ws[4];
    if ((t & 63) == 0) ws[t >> 6] = p;
    __syncthreads();
    if (t == 0) {
        const float s = ws[0] + ws[1] + ws[2] + ws[3] + bo[0];
        out2[row] = 1.f / (1.f + __expf(-s));
    }
}

// ---------------------------------------------------------------------------
extern "C" void kernel_launch(void* const* d_in, const int* in_sizes, int n_in,
                              void* d_out, int out_size, void* d_ws, size_t ws_size,
                              hipStream_t stream) {
    const float* input = (const float*)d_in[0];
    const float* W1 = (const float*)d_in[1];
    const float* b1 = (const float*)d_in[2];
    const float* W2 = (const float*)d_in[3];
    const float* b2 = (const float*)d_in[4];
    const float* Wh = (const float*)d_in[5];
    const float* bh = (const float*)d_in[6];
    const float* W3 = (const float*)d_in[7];
    const float* b3 = (const float*)d_in[8];
    const float* W4 = (const float*)d_in[9];
    const float* b4 = (const float*)d_in[10];
    const float* Wo = (const float*)d_in[11];
    const float* bo = (const float*)d_in[12];
    const float* T  = (const float*)d_in[13];

    unsigned short* inbf  = (unsigned short*)d_ws;                 // 2 MB
    unsigned short* W1t   = inbf  + (size_t)2048 * 512;            // 1 MB
    unsigned short* W2t   = W1t   + (size_t)1024 * 512;            // 3 MB
    unsigned short* Wht   = W2t   + (size_t)1536 * 1024;           // 4.5 MB
    unsigned short* W3t   = Wht   + (size_t)1536 * 1536;           // 3 MB
    unsigned short* W4t   = W3t   + (size_t)1024 * 1536;           // 1 MB
    unsigned short* Tt    = W4t   + (size_t)512 * 1024;            // 2 MB
    unsigned short* slabA = Tt    + (size_t)2048 * 512;            // 6 MB
    unsigned short* slabB = slabA + (size_t)2048 * 1536;           // 6 MB
    float* Ms  = (float*)(slabB + (size_t)2048 * 1536);            // 16 MB
    float* oT  = Ms + (size_t)2048 * 2048;                         // 1 MB
    float* nrm = oT + (size_t)2048 * 128;                          // 1 MB
    unsigned short* Msb = inbf;  // 8 MB, region dead by T-GEMM time

    unsigned short* x1bf   = slabA;
    unsigned short* x2bf   = slabB;
    unsigned short* x3bf   = slabA;
    unsigned short* x4bf   = slabB;
    unsigned short* featbf = slabA;

    float* feat = (float*)d_out;
    float* out2 = feat + (size_t)NROWS * HD;

    const dim3 blk(256);

    conv_bf16_kernel<<<1024, blk, 0, stream>>>(input, inbf, 2048 * 512 / 4);

    TransArgs ta;
    ta.src[0] = W1; ta.dst[0] = W1t; ta.K[0] =  512; ta.M[0] = 1024; ta.t0[0] = 0;
    ta.src[1] = W2; ta.dst[1] = W2t; ta.K[1] = 1024; ta.M[1] = 1536; ta.t0[1] = 512;
    ta.src[2] = Wh; ta.dst[2] = Wht; ta.K[2] = 1536; ta.M[2] = 1536; ta.t0[2] = 2048;
    ta.src[3] = W3; ta.dst[3] = W3t; ta.K[3] = 1536; ta.M[3] = 1024; ta.t0[3] = 4352;
    ta.src[4] = W4; ta.dst[4] = W4t; ta.K[4] = 1024; ta.M[4] =  512; ta.t0[4] = 5888;
    ta.src[5] = T;  ta.dst[5] = Tt;  ta.K[5] =  512; ta.M[5] = 2048; ta.t0[5] = 6400;
    trans_all_kernel<<<7424, blk, 0, stream>>>(ta);

    gemm128_kernel<1, 0, 1, 1, 0><<<dim3(1024 / 64, 16), blk, 0, stream>>>(inbf, W1t, b1, x1bf, nullptr, 512, 1024);
    gemm128_kernel<1, 0, 1, 1, 0><<<dim3(1536 / 64, 16), blk, 0, stream>>>(x1bf, W2t, b2, x2bf, nullptr, 1024, 1536);
    gemm128_kernel<1, 0, 1, 1, 0><<<dim3(1536 / 64, 16), blk, 0, stream>>>(x2bf, Wht, bh, x3bf, nullptr, 1536, 1536);
    gemm128_kernel<1, 0, 1, 1, 0><<<dim3(1024 / 64, 16), blk, 0, stream>>>(x3bf, W3t, b3, x4bf, nullptr, 1536, 1024);
    gemm64_kernel <1, 1, 1, 1>   <<<dim3( 512 / 64, 32), blk, 0, stream>>>(x4bf, W4t, b4, featbf, feat, 1024, 512);
    gemm128_kernel<1, 1, 0, 0, 1><<<dim3(2048 / 64, 16), blk, 0, stream>>>(featbf, Tt, nullptr, Msb, Ms, 512, 2048);

    norms_kernel<<<1024, blk, 0, stream>>>(Ms, nrm, oT);
    mbdisc32_kernel<<<dim3(2, 128), dim3(512), 73728, stream>>>(Ms, Msb, nrm, oT);

    logits_kernel<<<NROWS, blk, 0, stream>>>(feat, oT, Wo, bo, out2);
}

// Round 10
// 262.061 us; speedup vs baseline: 4.5092x; 1.0314x over previous
//
#include <hip/hip_runtime.h>
#include <hip/hip_bf16.h>
#include <math.h>

#define NROWS 2048
#define HD 512
#define DBx 128

typedef __attribute__((ext_vector_type(8)))  short bf16x8;
typedef __attribute__((ext_vector_type(4)))  float f32x4;
typedef __attribute__((ext_vector_type(16))) float f32x16;

__device__ inline unsigned pack2_bf16(float a, float b) {
    union { __hip_bfloat162 h; unsigned u; } cv;
    cv.h = __float22bfloat162_rn(make_float2(a, b));
    return cv.u;
}
__device__ inline unsigned short pack1_bf16(float a) {
    union { __hip_bfloat16 h; unsigned short u; } cv;
    cv.h = __float2bfloat16(a);
    return cv.u;
}

// ---------------------------------------------------------------------------
// f32 -> bf16 straight conversion (input activations).
// ---------------------------------------------------------------------------
__global__ __launch_bounds__(256) void conv_bf16_kernel(const float* __restrict__ in,
                                                        unsigned short* __restrict__ out,
                                                        int n4) {
    for (int idx = blockIdx.x * 256 + threadIdx.x; idx < n4; idx += gridDim.x * 256) {
        const float4 v = *reinterpret_cast<const float4*>(in + (size_t)idx * 4);
        uint2 o;
        o.x = pack2_bf16(v.x, v.y);
        o.y = pack2_bf16(v.z, v.w);
        *reinterpret_cast<uint2*>(out + (size_t)idx * 4) = o;
    }
}

// ---------------------------------------------------------------------------
// All 6 weight transposes (f32 [K][M] -> bf16 [M][K]) in ONE kernel.
// ---------------------------------------------------------------------------
struct TransArgs {
    const float* src[6];
    unsigned short* dst[6];
    int K[6], M[6], t0[6];
};

__global__ __launch_bounds__(256) void trans_all_kernel(TransArgs a) {
    const int id = blockIdx.x;
    int m = 0;
    #pragma unroll
    for (int q = 1; q < 6; ++q) if (id >= a.t0[q]) m = q;
    const int local = id - a.t0[m];
    const int M = a.M[m], K = a.K[m];
    const int ntm = M >> 5;
    const int mt = local % ntm;
    const int kt = local / ntm;
    const float* W = a.src[m];
    unsigned short* Wt = a.dst[m];

    __shared__ float tile[32][33];
    const int t  = threadIdx.x;
    const int tr = t >> 3;
    const int tc = t & 7;
    const int k0 = kt * 32;
    const int m0 = mt * 32;

    const float4 v = *reinterpret_cast<const float4*>(&W[(size_t)(k0 + tr) * M + m0 + tc * 4]);
    tile[tr][tc * 4 + 0] = v.x;
    tile[tr][tc * 4 + 1] = v.y;
    tile[tr][tc * 4 + 2] = v.z;
    tile[tr][tc * 4 + 3] = v.w;
    __syncthreads();

    const float x = tile[tc * 4 + 0][tr];
    const float y = tile[tc * 4 + 1][tr];
    const float z = tile[tc * 4 + 2][tr];
    const float w = tile[tc * 4 + 3][tr];
    uint2 o;
    o.x = pack2_bf16(x, y);
    o.y = pack2_bf16(z, w);
    *reinterpret_cast<uint2*>(&Wt[(size_t)(m0 + tr) * K + k0 + tc * 4]) = o;
}

// ---------------------------------------------------------------------------
// bf16 MFMA GEMM, 64x64 tile, BK=64, 4 waves (2x2), 2-phase double-buffered
// global_load_lds pipeline. A bf16 [rows][K], Bt bf16 [M][K].
// XOR 16B-chunk swizzle ch^(row&7).
// MSB: additionally write bf16 C in per-b layout Msb[(col>>4)][row][col&15].
// ---------------------------------------------------------------------------
template<int WRITE_BF16, int WRITE_F32, int RELU, int BIAS, int MSB>
__global__ __launch_bounds__(256) void gemm64_kernel(const unsigned short* __restrict__ Abf,
                                                     const unsigned short* __restrict__ Bt,
                                                     const float* __restrict__ bias,
                                                     unsigned short* __restrict__ Cbf,
                                                     float* __restrict__ Cf,
                                                     int K, int M) {
    __shared__ unsigned short As[2][64 * 64];
    __shared__ unsigned short Bs[2][64 * 64];

    const int t    = threadIdx.x;
    const int lane = t & 63;
    const int wv   = t >> 6;
    const int wm   = wv & 1;
    const int wn   = wv >> 1;
    const int row0 = blockIdx.y * 64;
    const int col0 = blockIdx.x * 64;
    const int gl_r = lane >> 3;
    const int gl_c = lane & 7;

    f32x4 acc[2][2] = {};

    auto STAGE = [&](int bufi, int kt) {
        #pragma unroll
        for (int q = 0; q < 2; ++q) {
            const int r = wv * 16 + q * 8 + gl_r;
            const unsigned short* srcA = Abf + (size_t)(row0 + r) * K + kt + 8 * (gl_c ^ (r & 7));
            __builtin_amdgcn_global_load_lds(
                (const __attribute__((address_space(1))) void*)srcA,
                (__attribute__((address_space(3))) void*)(&As[bufi][(wv * 16 + q * 8) * 64]),
                16, 0, 0);
            const unsigned short* srcB = Bt + (size_t)(col0 + r) * K + kt + 8 * (gl_c ^ (r & 7));
            __builtin_amdgcn_global_load_lds(
                (const __attribute__((address_space(1))) void*)srcB,
                (__attribute__((address_space(3))) void*)(&Bs[bufi][(wv * 16 + q * 8) * 64]),
                16, 0, 0);
        }
    };

    const int nkt = K >> 6;
    STAGE(0, 0);
    __syncthreads();
    int buf = 0;
    for (int kt = 0; kt < nkt; ++kt) {
        if (kt + 1 < nkt) STAGE(buf ^ 1, (kt + 1) * 64);
        const int lm = lane & 15;
        const int kg = lane >> 4;
        #pragma unroll
        for (int ks = 0; ks < 2; ++ks) {
            bf16x8 af[2], bfr[2];
            #pragma unroll
            for (int fi = 0; fi < 2; ++fi) {
                const int r  = wm * 32 + fi * 16 + lm;
                const int ch = (kg + 4 * ks) ^ (r & 7);
                af[fi] = *reinterpret_cast<const bf16x8*>((const char*)&As[buf][0] + r * 128 + ch * 16);
            }
            #pragma unroll
            for (int fj = 0; fj < 2; ++fj) {
                const int n  = wn * 32 + fj * 16 + lm;
                const int ch = (kg + 4 * ks) ^ (n & 7);
                bfr[fj] = *reinterpret_cast<const bf16x8*>((const char*)&Bs[buf][0] + n * 128 + ch * 16);
            }
            #pragma unroll
            for (int fi = 0; fi < 2; ++fi)
                #pragma unroll
                for (int fj = 0; fj < 2; ++fj)
                    acc[fi][fj] = __builtin_amdgcn_mfma_f32_16x16x32_bf16(
                        af[fi], bfr[fj], acc[fi][fj], 0, 0, 0);
        }
        __syncthreads();
        buf ^= 1;
    }

    const int lm = lane & 15;
    const int lq = lane >> 4;
    #pragma unroll
    for (int fj = 0; fj < 2; ++fj) {
        const int col = col0 + wn * 32 + fj * 16 + lm;
        const float bv = BIAS ? bias[col] : 0.f;
        #pragma unroll
        for (int fi = 0; fi < 2; ++fi) {
            #pragma unroll
            for (int r = 0; r < 4; ++r) {
                const int row = row0 + wm * 32 + fi * 16 + lq * 4 + r;
                float v = acc[fi][fj][r] + bv;
                if (RELU) v = fmaxf(v, 0.f);
                if (WRITE_F32)  Cf[(size_t)row * M + col] = v;
                if (WRITE_BF16) {
                    if (MSB)
                        Cbf[(size_t)(col >> 4) * (NROWS * 16) + (size_t)row * 16 + (col & 15)] = pack1_bf16(v);
                    else
                        Cbf[(size_t)row * M + col] = pack1_bf16(v);
                }
            }
        }
    }
}

// ---------------------------------------------------------------------------
// Row norms (scaled 0.495) + zero outT.
// ---------------------------------------------------------------------------
__global__ __launch_bounds__(256) void norms_kernel(const float* __restrict__ Ms,
                                                    float* __restrict__ nrm,
                                                    float* __restrict__ oT) {
    const int g = blockIdx.x * 256 + threadIdx.x;
    const int i = g >> 7;
    const int b = g & 127;
    const float* p = Ms + (size_t)i * 2048 + b * 16;
    float s = 0.f;
    #pragma unroll
    for (int c = 0; c < 16; c += 4) {
        const float4 v = *reinterpret_cast<const float4*>(p + c);
        s += v.x * v.x + v.y * v.y + v.z * v.z + v.w * v.w;
    }
    nrm[(size_t)b * 2048 + i] = 0.495f * s;
    oT[g] = 0.f;
}

// ---------------------------------------------------------------------------
// MFMA-gated minibatch discrimination v5.
// Grid (2 i-half, 128 b, 2 j-half), 512 thr. Each block stages its j-half
// slab (32KB, [h][jj][16B]) + j-half nrm (4KB) => 36KB LDS => 2 blocks/CU,
// 4 waves/SIMD (2x the TLP of v4). i-side nrm / A-frags from global (L2).
// Inner loop: 2 j-tiles per iteration with DEFERRED gate (2 MFMAs + 2 fmax
// trees issue back-to-back; one __any per pair) for ILP across MFMA latency.
// Gate algebra identical to R4-proven: acc = dot + 725 - 0.495 n_i; pass iff
// acc[r] > 0.495 n_j  (skip <=> 0.99(n_i+n_j) - 2 dot >= 1450; skipped mass
// < 2048 e^-36 for ANY input). Passers recompute exact f32 L1 from Ms.
// ---------------------------------------------------------------------------
__global__ __launch_bounds__(512) void mbdisc32_kernel(const float* __restrict__ Ms,
                                                       const unsigned short* __restrict__ Msb,
                                                       const float* __restrict__ nrm,
                                                       float* __restrict__ outT) {
    extern __shared__ char smem[];                       // 32KB slab + 4KB nrm
    float* Nlds = (float*)(smem + 32768);

    const int t    = threadIdx.x;
    const int lane = t & 63;
    const int w    = t >> 6;                             // 0..7
    const int b    = blockIdx.y;
    const int jh   = blockIdx.z;                         // j-half
    const int cl   = lane & 31;
    const int hk   = lane >> 5;
    const int jbase = jh * 1024;

    const unsigned short* Mb = Msb + (size_t)b * NROWS * 16;
    const float* nb = nrm + (size_t)b * NROWS;

    // stage slab half: slot s = h*1024 + jj -> lds byte s*16
    #pragma unroll
    for (int q = 0; q < 4; ++q) {
        const int slot = q * 512 + t;
        const int h = slot >> 10, jj = slot & 1023;
        const unsigned short* src = Mb + (size_t)(jbase + jj) * 16 + h * 8;
        __builtin_amdgcn_global_load_lds(
            (const __attribute__((address_space(1))) void*)src,
            (__attribute__((address_space(3))) void*)(smem + (size_t)(q * 512 + w * 64) * 16),
            16, 0, 0);
    }
    if (w < 4) {   // stage j-half nrm: 1024 f32 = 4KB = 4 waves x 64 lanes x 16B
        const float* src = nb + jbase + (w * 64 + lane) * 4;
        __builtin_amdgcn_global_load_lds(
            (const __attribute__((address_space(1))) void*)src,
            (__attribute__((address_space(3))) void*)(smem + 32768 + (size_t)(w * 64) * 16),
            16, 0, 0);
    }

    // A-frags for all 4 i-chunks from global (L2-hot), issued before barrier
    bf16x8 afc[4];
    #pragma unroll
    for (int ic = 0; ic < 4; ++ic) {
        const int i0 = blockIdx.x * 1024 + w * 128 + ic * 32;
        afc[ic] = *reinterpret_cast<const bf16x8*>(Mb + (size_t)(i0 + cl) * 16 + hk * 8);
    }
    __syncthreads();

    const char* mrow = smem + hk * 16384;

    #pragma unroll
    for (int ic = 0; ic < 4; ++ic) {
        const int i0 = blockIdx.x * 1024 + w * 128 + ic * 32;
        const bf16x8 af = afc[ic];

        // loop-invariant C-in from global nrm: cI[r] = 725 - 0.495 n_i
        f32x16 cI;
        #pragma unroll
        for (int q = 0; q < 4; ++q) {
            const float4 v = *reinterpret_cast<const float4*>(nb + i0 + 4 * hk + 8 * q);
            cI[4 * q + 0] = 725.f - v.x; cI[4 * q + 1] = 725.f - v.y;
            cI[4 * q + 2] = 725.f - v.z; cI[4 * q + 3] = 725.f - v.w;
        }

        #pragma unroll 2
        for (int j0 = 0; j0 < 1024; j0 += 64) {
            const float nj0 = Nlds[j0 + cl];
            const float nj1 = Nlds[j0 + 32 + cl];
            const bf16x8 b0 = *reinterpret_cast<const bf16x8*>(mrow + (size_t)(j0 + cl) * 16);
            const bf16x8 b1 = *reinterpret_cast<const bf16x8*>(mrow + (size_t)(j0 + 32 + cl) * 16);
            const f32x16 a0 = __builtin_amdgcn_mfma_f32_32x32x16_bf16(af, b0, cI, 0, 0, 0);
            const f32x16 a1 = __builtin_amdgcn_mfma_f32_32x32x16_bf16(af, b1, cI, 0, 0, 0);

            float x0 = fmaxf(fmaxf(a0[0], a0[1]), fmaxf(a0[2], a0[3]));
            float x1 = fmaxf(fmaxf(a0[4], a0[5]), fmaxf(a0[6], a0[7]));
            float x2 = fmaxf(fmaxf(a0[8], a0[9]), fmaxf(a0[10], a0[11]));
            float x3 = fmaxf(fmaxf(a0[12], a0[13]), fmaxf(a0[14], a0[15]));
            const float mx0 = fmaxf(fmaxf(x0, x1), fmaxf(x2, x3));
            float y0 = fmaxf(fmaxf(a1[0], a1[1]), fmaxf(a1[2], a1[3]));
            float y1 = fmaxf(fmaxf(a1[4], a1[5]), fmaxf(a1[6], a1[7]));
            float y2 = fmaxf(fmaxf(a1[8], a1[9]), fmaxf(a1[10], a1[11]));
            float y3 = fmaxf(fmaxf(a1[12], a1[13]), fmaxf(a1[14], a1[15]));
            const float mx1 = fmaxf(fmaxf(y0, y1), fmaxf(y2, y3));

            if (__any(fmaxf(mx0 - nj0, mx1 - nj1) > 0.f)) {
                #pragma unroll
                for (int r = 0; r < 16; ++r) {
                    if (a0[r] > nj0) {
                        const int i = i0 + (r & 3) + 8 * (r >> 2) + 4 * hk;
                        const int j = jbase + j0 + cl;
                        const float* pi = Ms + (size_t)i * 2048 + b * 16;
                        const float* pj = Ms + (size_t)j * 2048 + b * 16;
                        float s = 0.f;
                        #pragma unroll
                        for (int cc = 0; cc < 16; cc += 4) {
                            const float4 x = *reinterpret_cast<const float4*>(pi + cc);
                            const float4 y = *reinterpret_cast<const float4*>(pj + cc);
                            s += (fabsf(x.x - y.x) + fabsf(x.y - y.y)) +
                                 (fabsf(x.z - y.z) + fabsf(x.w - y.w));
                        }
                        atomicAdd(&outT[(size_t)i * DBx + b], __expf(-s));
                    }
                }
                #pragma unroll
                for (int r = 0; r < 16; ++r) {
                    if (a1[r] > nj1) {
                        const int i = i0 + (r & 3) + 8 * (r >> 2) + 4 * hk;
                        const int j = jbase + j0 + 32 + cl;
                        const float* pi = Ms + (size_t)i * 2048 + b * 16;
                        const float* pj = Ms + (size_t)j * 2048 + b * 16;
                        float s = 0.f;
                        #pragma unroll
                        for (int cc = 0; cc < 16; cc += 4) {
                            const float4 x = *reinterpret_cast<const float4*>(pi + cc);
                            const float4 y = *reinterpret_cast<const float4*>(pj + cc);
                            s += (fabsf(x.x - y.x) + fabsf(x.y - y.y)) +
                                 (fabsf(x.z - y.z) + fabsf(x.w - y.w));
                        }
                        atomicAdd(&outT[(size_t)i * DBx + b], __expf(-s));
                    }
                }
            }
        }
    }
}

// ---------------------------------------------------------------------------
// logits = sigmoid(concat(feature, outT) @ Wo + bo). One block per row.
// ---------------------------------------------------------------------------
__global__ __launch_bounds__(256) void logits_kernel(const float* __restrict__ feat,
                                                     const float* __restrict__ outT,
                                                     const float* __restrict__ Wo,
                                                     const float* __restrict__ bo,
                                                     float* __restrict__ out2) {
    const int row = blockIdx.x;
    const int t   = threadIdx.x;
    float p = 0.f;
    for (int k = t; k < HD + DBx; k += 256) {
        const float x = (k < HD) ? feat[(size_t)row * HD + k]
                                 : outT[(size_t)row * DBx + (k - HD)];
        p += x * Wo[k];
    }
    #pragma unroll
    for (int off = 32; off; off >>= 1) p += __shfl_down(p, off, 64);
    __shared__ float ws[4];
    if ((t & 63) == 0) ws[t >> 6] = p;
    __syncthreads();
    if (t == 0) {
        const float s = ws[0] + ws[1] + ws[2] + ws[3] + bo[0];
        out2[row] = 1.f / (1.f + __expf(-s));
    }
}

// ---------------------------------------------------------------------------
extern "C" void kernel_launch(void* const* d_in, const int* in_sizes, int n_in,
                              void* d_out, int out_size, void* d_ws, size_t ws_size,
                              hipStream_t stream) {
    const float* input = (const float*)d_in[0];
    const float* W1 = (const float*)d_in[1];
    const float* b1 = (const float*)d_in[2];
    const float* W2 = (const float*)d_in[3];
    const float* b2 = (const float*)d_in[4];
    const float* Wh = (const float*)d_in[5];
    const float* bh = (const float*)d_in[6];
    const float* W3 = (const float*)d_in[7];
    const float* b3 = (const float*)d_in[8];
    const float* W4 = (const float*)d_in[9];
    const float* b4 = (const float*)d_in[10];
    const float* Wo = (const float*)d_in[11];
    const float* bo = (const float*)d_in[12];
    const float* T  = (const float*)d_in[13];

    unsigned short* inbf  = (unsigned short*)d_ws;                 // 2 MB
    unsigned short* W1t   = inbf  + (size_t)2048 * 512;            // 1 MB
    unsigned short* W2t   = W1t   + (size_t)1024 * 512;            // 3 MB
    unsigned short* Wht   = W2t   + (size_t)1536 * 1024;           // 4.5 MB
    unsigned short* W3t   = Wht   + (size_t)1536 * 1536;           // 3 MB
    unsigned short* W4t   = W3t   + (size_t)1024 * 1536;           // 1 MB
    unsigned short* Tt    = W4t   + (size_t)512 * 1024;            // 2 MB
    unsigned short* slabA = Tt    + (size_t)2048 * 512;            // 6 MB
    unsigned short* slabB = slabA + (size_t)2048 * 1536;           // 6 MB
    float* Ms  = (float*)(slabB + (size_t)2048 * 1536);            // 16 MB
    float* oT  = Ms + (size_t)2048 * 2048;                         // 1 MB
    float* nrm = oT + (size_t)2048 * 128;                          // 1 MB
    unsigned short* Msb = inbf;  // 8 MB, region dead by T-GEMM time

    unsigned short* x1bf   = slabA;
    unsigned short* x2bf   = slabB;
    unsigned short* x3bf   = slabA;
    unsigned short* x4bf   = slabB;
    unsigned short* featbf = slabA;

    float* feat = (float*)d_out;
    float* out2 = feat + (size_t)NROWS * HD;

    const dim3 blk(256);

    conv_bf16_kernel<<<1024, blk, 0, stream>>>(input, inbf, 2048 * 512 / 4);

    TransArgs ta;
    ta.src[0] = W1; ta.dst[0] = W1t; ta.K[0] =  512; ta.M[0] = 1024; ta.t0[0] = 0;
    ta.src[1] = W2; ta.dst[1] = W2t; ta.K[1] = 1024; ta.M[1] = 1536; ta.t0[1] = 512;
    ta.src[2] = Wh; ta.dst[2] = Wht; ta.K[2] = 1536; ta.M[2] = 1536; ta.t0[2] = 2048;
    ta.src[3] = W3; ta.dst[3] = W3t; ta.K[3] = 1536; ta.M[3] = 1024; ta.t0[3] = 4352;
    ta.src[4] = W4; ta.dst[4] = W4t; ta.K[4] = 1024; ta.M[4] =  512; ta.t0[4] = 5888;
    ta.src[5] = T;  ta.dst[5] = Tt;  ta.K[5] =  512; ta.M[5] = 2048; ta.t0[5] = 6400;
    trans_all_kernel<<<7424, blk, 0, stream>>>(ta);

    gemm64_kernel<1, 0, 1, 1, 0><<<dim3(1024 / 64, 32), blk, 0, stream>>>(inbf, W1t, b1, x1bf, nullptr, 512, 1024);
    gemm64_kernel<1, 0, 1, 1, 0><<<dim3(1536 / 64, 32), blk, 0, stream>>>(x1bf, W2t, b2, x2bf, nullptr, 1024, 1536);
    gemm64_kernel<1, 0, 1, 1, 0><<<dim3(1536 / 64, 32), blk, 0, stream>>>(x2bf, Wht, bh, x3bf, nullptr, 1536, 1536);
    gemm64_kernel<1, 0, 1, 1, 0><<<dim3(1024 / 64, 32), blk, 0, stream>>>(x3bf, W3t, b3, x4bf, nullptr, 1536, 1024);
    gemm64_kernel<1, 1, 1, 1, 0><<<dim3( 512 / 64, 32), blk, 0, stream>>>(x4bf, W4t, b4, featbf, feat, 1024, 512);
    gemm64_kernel<1, 1, 0, 0, 1><<<dim3(2048 / 64, 32), blk, 0, stream>>>(featbf, Tt, nullptr, Msb, Ms, 512, 2048);

    norms_kernel<<<1024, blk, 0, stream>>>(Ms, nrm, oT);
    mbdisc32_kernel<<<dim3(2, 128, 2), dim3(512), 36864, stream>>>(Ms, Msb, nrm, oT);

    logits_kernel<<<NROWS, blk, 0, stream>>>(feat, oT, Wo, bo, out2);
}

// Round 11
// 228.785 us; speedup vs baseline: 5.1651x; 1.1454x over previous
//
#include <hip/hip_runtime.h>
#include <hip/hip_bf16.h>
#include <math.h>

#define NROWS 2048
#define HD 512
#define DBx 128

typedef __attribute__((ext_vector_type(8)))  short bf16x8;
typedef __attribute__((ext_vector_type(4)))  float f32x4;
typedef __attribute__((ext_vector_type(16))) float f32x16;

__device__ inline unsigned pack2_bf16(float a, float b) {
    union { __hip_bfloat162 h; unsigned u; } cv;
    cv.h = __float22bfloat162_rn(make_float2(a, b));
    return cv.u;
}
__device__ inline unsigned short pack1_bf16(float a) {
    union { __hip_bfloat16 h; unsigned short u; } cv;
    cv.h = __float2bfloat16(a);
    return cv.u;
}

// ---------------------------------------------------------------------------
// f32 -> bf16 straight conversion (input activations).
// ---------------------------------------------------------------------------
__global__ __launch_bounds__(256) void conv_bf16_kernel(const float* __restrict__ in,
                                                        unsigned short* __restrict__ out,
                                                        int n4) {
    for (int idx = blockIdx.x * 256 + threadIdx.x; idx < n4; idx += gridDim.x * 256) {
        const float4 v = *reinterpret_cast<const float4*>(in + (size_t)idx * 4);
        uint2 o;
        o.x = pack2_bf16(v.x, v.y);
        o.y = pack2_bf16(v.z, v.w);
        *reinterpret_cast<uint2*>(out + (size_t)idx * 4) = o;
    }
}

// ---------------------------------------------------------------------------
// All 6 weight transposes (f32 [K][M] -> bf16 [M][K]) in ONE kernel.
// ---------------------------------------------------------------------------
struct TransArgs {
    const float* src[6];
    unsigned short* dst[6];
    int K[6], M[6], t0[6];
};

__global__ __launch_bounds__(256) void trans_all_kernel(TransArgs a) {
    const int id = blockIdx.x;
    int m = 0;
    #pragma unroll
    for (int q = 1; q < 6; ++q) if (id >= a.t0[q]) m = q;
    const int local = id - a.t0[m];
    const int M = a.M[m], K = a.K[m];
    const int ntm = M >> 5;
    const int mt = local % ntm;
    const int kt = local / ntm;
    const float* W = a.src[m];
    unsigned short* Wt = a.dst[m];

    __shared__ float tile[32][33];
    const int t  = threadIdx.x;
    const int tr = t >> 3;
    const int tc = t & 7;
    const int k0 = kt * 32;
    const int m0 = mt * 32;

    const float4 v = *reinterpret_cast<const float4*>(&W[(size_t)(k0 + tr) * M + m0 + tc * 4]);
    tile[tr][tc * 4 + 0] = v.x;
    tile[tr][tc * 4 + 1] = v.y;
    tile[tr][tc * 4 + 2] = v.z;
    tile[tr][tc * 4 + 3] = v.w;
    __syncthreads();

    const float x = tile[tc * 4 + 0][tr];
    const float y = tile[tc * 4 + 1][tr];
    const float z = tile[tc * 4 + 2][tr];
    const float w = tile[tc * 4 + 3][tr];
    uint2 o;
    o.x = pack2_bf16(x, y);
    o.y = pack2_bf16(z, w);
    *reinterpret_cast<uint2*>(&Wt[(size_t)(m0 + tr) * K + k0 + tc * 4]) = o;
}

// ---------------------------------------------------------------------------
// bf16 MFMA GEMM, 64x64 tile, BK=64, 4 waves (2x2), 2-phase double-buffered
// global_load_lds pipeline. A bf16 [rows][K], Bt bf16 [M][K].
// XOR 16B-chunk swizzle ch^(row&7).
// MSB: additionally write bf16 C in per-b layout Msb[(col>>4)][row][col&15].
// ---------------------------------------------------------------------------
template<int WRITE_BF16, int WRITE_F32, int RELU, int BIAS, int MSB>
__global__ __launch_bounds__(256) void gemm64_kernel(const unsigned short* __restrict__ Abf,
                                                     const unsigned short* __restrict__ Bt,
                                                     const float* __restrict__ bias,
                                                     unsigned short* __restrict__ Cbf,
                                                     float* __restrict__ Cf,
                                                     int K, int M) {
    __shared__ unsigned short As[2][64 * 64];
    __shared__ unsigned short Bs[2][64 * 64];

    const int t    = threadIdx.x;
    const int lane = t & 63;
    const int wv   = t >> 6;
    const int wm   = wv & 1;
    const int wn   = wv >> 1;
    const int row0 = blockIdx.y * 64;
    const int col0 = blockIdx.x * 64;
    const int gl_r = lane >> 3;
    const int gl_c = lane & 7;

    f32x4 acc[2][2] = {};

    auto STAGE = [&](int bufi, int kt) {
        #pragma unroll
        for (int q = 0; q < 2; ++q) {
            const int r = wv * 16 + q * 8 + gl_r;
            const unsigned short* srcA = Abf + (size_t)(row0 + r) * K + kt + 8 * (gl_c ^ (r & 7));
            __builtin_amdgcn_global_load_lds(
                (const __attribute__((address_space(1))) void*)srcA,
                (__attribute__((address_space(3))) void*)(&As[bufi][(wv * 16 + q * 8) * 64]),
                16, 0, 0);
            const unsigned short* srcB = Bt + (size_t)(col0 + r) * K + kt + 8 * (gl_c ^ (r & 7));
            __builtin_amdgcn_global_load_lds(
                (const __attribute__((address_space(1))) void*)srcB,
                (__attribute__((address_space(3))) void*)(&Bs[bufi][(wv * 16 + q * 8) * 64]),
                16, 0, 0);
        }
    };

    const int nkt = K >> 6;
    STAGE(0, 0);
    __syncthreads();
    int buf = 0;
    for (int kt = 0; kt < nkt; ++kt) {
        if (kt + 1 < nkt) STAGE(buf ^ 1, (kt + 1) * 64);
        const int lm = lane & 15;
        const int kg = lane >> 4;
        #pragma unroll
        for (int ks = 0; ks < 2; ++ks) {
            bf16x8 af[2], bfr[2];
            #pragma unroll
            for (int fi = 0; fi < 2; ++fi) {
                const int r  = wm * 32 + fi * 16 + lm;
                const int ch = (kg + 4 * ks) ^ (r & 7);
                af[fi] = *reinterpret_cast<const bf16x8*>((const char*)&As[buf][0] + r * 128 + ch * 16);
            }
            #pragma unroll
            for (int fj = 0; fj < 2; ++fj) {
                const int n  = wn * 32 + fj * 16 + lm;
                const int ch = (kg + 4 * ks) ^ (n & 7);
                bfr[fj] = *reinterpret_cast<const bf16x8*>((const char*)&Bs[buf][0] + n * 128 + ch * 16);
            }
            #pragma unroll
            for (int fi = 0; fi < 2; ++fi)
                #pragma unroll
                for (int fj = 0; fj < 2; ++fj)
                    acc[fi][fj] = __builtin_amdgcn_mfma_f32_16x16x32_bf16(
                        af[fi], bfr[fj], acc[fi][fj], 0, 0, 0);
        }
        __syncthreads();
        buf ^= 1;
    }

    const int lm = lane & 15;
    const int lq = lane >> 4;
    #pragma unroll
    for (int fj = 0; fj < 2; ++fj) {
        const int col = col0 + wn * 32 + fj * 16 + lm;
        const float bv = BIAS ? bias[col] : 0.f;
        #pragma unroll
        for (int fi = 0; fi < 2; ++fi) {
            #pragma unroll
            for (int r = 0; r < 4; ++r) {
                const int row = row0 + wm * 32 + fi * 16 + lq * 4 + r;
                float v = acc[fi][fj][r] + bv;
                if (RELU) v = fmaxf(v, 0.f);
                if (WRITE_F32)  Cf[(size_t)row * M + col] = v;
                if (WRITE_BF16) {
                    if (MSB)
                        Cbf[(size_t)(col >> 4) * (NROWS * 16) + (size_t)row * 16 + (col & 15)] = pack1_bf16(v);
                    else
                        Cbf[(size_t)row * M + col] = pack1_bf16(v);
                }
            }
        }
    }
}

// ---------------------------------------------------------------------------
// Row norms (scaled 0.495) + init outT to 1.0 (the exact j==i diagonal term,
// elided from the pair loop).
// ---------------------------------------------------------------------------
__global__ __launch_bounds__(256) void norms_kernel(const float* __restrict__ Ms,
                                                    float* __restrict__ nrm,
                                                    float* __restrict__ oT) {
    const int g = blockIdx.x * 256 + threadIdx.x;
    const int i = g >> 7;
    const int b = g & 127;
    const float* p = Ms + (size_t)i * 2048 + b * 16;
    float s = 0.f;
    #pragma unroll
    for (int c = 0; c < 16; c += 4) {
        const float4 v = *reinterpret_cast<const float4*>(p + c);
        s += v.x * v.x + v.y * v.y + v.z * v.z + v.w * v.w;
    }
    nrm[(size_t)b * 2048 + i] = 0.495f * s;
    oT[g] = 1.0f;
}

// ---------------------------------------------------------------------------
// MFMA-gated minibatch discrimination v6 = v5 + diagonal elision + max3 tree.
// Grid (2 i-half, 128 b, 2 j-half), 512 thr, 36KB LDS (j-half slab + nrm).
// Gate (R4-proven): acc = dot + 725 - 0.495 n_i; pass iff acc[r] > 0.495 n_j
// (skip <=> 0.99(n_i+n_j) - 2 dot >= 1450; skipped mass < 2048 e^-36).
// j==i hits are SKIPPED (their exact term exp(0)=1.0 is pre-added in outT
// init) -> the always-firing diagonal tiles cost only the cmp loop; heavy
// exact-L1 path runs only for true near-duplicate pairs (~0). This removes
// the ih==jh block imbalance that capped v5 at 20% occupancy.
// ---------------------------------------------------------------------------
__global__ __launch_bounds__(512) void mbdisc32_kernel(const float* __restrict__ Ms,
                                                       const unsigned short* __restrict__ Msb,
                                                       const float* __restrict__ nrm,
                                                       float* __restrict__ outT) {
    extern __shared__ char smem[];                       // 32KB slab + 4KB nrm
    float* Nlds = (float*)(smem + 32768);

    const int t    = threadIdx.x;
    const int lane = t & 63;
    const int w    = t >> 6;                             // 0..7
    const int b    = blockIdx.y;
    const int jh   = blockIdx.z;                         // j-half
    const int cl   = lane & 31;
    const int hk   = lane >> 5;
    const int jbase = jh * 1024;

    const unsigned short* Mb = Msb + (size_t)b * NROWS * 16;
    const float* nb = nrm + (size_t)b * NROWS;

    // stage slab half: slot s = h*1024 + jj -> lds byte s*16
    #pragma unroll
    for (int q = 0; q < 4; ++q) {
        const int slot = q * 512 + t;
        const int h = slot >> 10, jj = slot & 1023;
        const unsigned short* src = Mb + (size_t)(jbase + jj) * 16 + h * 8;
        __builtin_amdgcn_global_load_lds(
            (const __attribute__((address_space(1))) void*)src,
            (__attribute__((address_space(3))) void*)(smem + (size_t)(q * 512 + w * 64) * 16),
            16, 0, 0);
    }
    if (w < 4) {   // stage j-half nrm: 1024 f32 = 4KB
        const float* src = nb + jbase + (w * 64 + lane) * 4;
        __builtin_amdgcn_global_load_lds(
            (const __attribute__((address_space(1))) void*)src,
            (__attribute__((address_space(3))) void*)(smem + 32768 + (size_t)(w * 64) * 16),
            16, 0, 0);
    }

    // A-frags for all 4 i-chunks from global (L2-hot), issued before barrier
    bf16x8 afc[4];
    #pragma unroll
    for (int ic = 0; ic < 4; ++ic) {
        const int i0 = blockIdx.x * 1024 + w * 128 + ic * 32;
        afc[ic] = *reinterpret_cast<const bf16x8*>(Mb + (size_t)(i0 + cl) * 16 + hk * 8);
    }
    __syncthreads();

    const char* mrow = smem + hk * 16384;

    #pragma unroll
    for (int ic = 0; ic < 4; ++ic) {
        const int i0 = blockIdx.x * 1024 + w * 128 + ic * 32;
        const bf16x8 af = afc[ic];

        // loop-invariant C-in: cI[r] = 725 - 0.495 n_i
        f32x16 cI;
        #pragma unroll
        for (int q = 0; q < 4; ++q) {
            const float4 v = *reinterpret_cast<const float4*>(nb + i0 + 4 * hk + 8 * q);
            cI[4 * q + 0] = 725.f - v.x; cI[4 * q + 1] = 725.f - v.y;
            cI[4 * q + 2] = 725.f - v.z; cI[4 * q + 3] = 725.f - v.w;
        }

        #pragma unroll 2
        for (int j0 = 0; j0 < 1024; j0 += 64) {
            const float nj0 = Nlds[j0 + cl];
            const float nj1 = Nlds[j0 + 32 + cl];
            const bf16x8 b0 = *reinterpret_cast<const bf16x8*>(mrow + (size_t)(j0 + cl) * 16);
            const bf16x8 b1 = *reinterpret_cast<const bf16x8*>(mrow + (size_t)(j0 + 32 + cl) * 16);
            const f32x16 a0 = __builtin_amdgcn_mfma_f32_32x32x16_bf16(af, b0, cI, 0, 0, 0);
            const f32x16 a1 = __builtin_amdgcn_mfma_f32_32x32x16_bf16(af, b1, cI, 0, 0, 0);

            // max3-fusable trees (8 ops each)
            const float p0 = fmaxf(fmaxf(a0[0],  a0[1]),  a0[2]);
            const float p1 = fmaxf(fmaxf(a0[3],  a0[4]),  a0[5]);
            const float p2 = fmaxf(fmaxf(a0[6],  a0[7]),  a0[8]);
            const float p3 = fmaxf(fmaxf(a0[9],  a0[10]), a0[11]);
            const float p4 = fmaxf(fmaxf(a0[12], a0[13]), a0[14]);
            const float mx0 = fmaxf(fmaxf(fmaxf(p0, p1), a0[15]),
                                    fmaxf(fmaxf(p2, p3), p4));
            const float q0 = fmaxf(fmaxf(a1[0],  a1[1]),  a1[2]);
            const float q1 = fmaxf(fmaxf(a1[3],  a1[4]),  a1[5]);
            const float q2 = fmaxf(fmaxf(a1[6],  a1[7]),  a1[8]);
            const float q3 = fmaxf(fmaxf(a1[9],  a1[10]), a1[11]);
            const float q4 = fmaxf(fmaxf(a1[12], a1[13]), a1[14]);
            const float mx1 = fmaxf(fmaxf(fmaxf(q0, q1), a1[15]),
                                    fmaxf(fmaxf(q2, q3), q4));

            if (__any((mx0 > nj0) || (mx1 > nj1))) {
                #pragma unroll
                for (int r = 0; r < 16; ++r) {
                    if (a0[r] > nj0) {
                        const int i = i0 + (r & 3) + 8 * (r >> 2) + 4 * hk;
                        const int j = jbase + j0 + cl;
                        if (j != i) {
                            const float* pi = Ms + (size_t)i * 2048 + b * 16;
                            const float* pj = Ms + (size_t)j * 2048 + b * 16;
                            float s = 0.f;
                            #pragma unroll
                            for (int cc = 0; cc < 16; cc += 4) {
                                const float4 x = *reinterpret_cast<const float4*>(pi + cc);
                                const float4 y = *reinterpret_cast<const float4*>(pj + cc);
                                s += (fabsf(x.x - y.x) + fabsf(x.y - y.y)) +
                                     (fabsf(x.z - y.z) + fabsf(x.w - y.w));
                            }
                            atomicAdd(&outT[(size_t)i * DBx + b], __expf(-s));
                        }
                    }
                }
                #pragma unroll
                for (int r = 0; r < 16; ++r) {
                    if (a1[r] > nj1) {
                        const int i = i0 + (r & 3) + 8 * (r >> 2) + 4 * hk;
                        const int j = jbase + j0 + 32 + cl;
                        if (j != i) {
                            const float* pi = Ms + (size_t)i * 2048 + b * 16;
                            const float* pj = Ms + (size_t)j * 2048 + b * 16;
                            float s = 0.f;
                            #pragma unroll
                            for (int cc = 0; cc < 16; cc += 4) {
                                const float4 x = *reinterpret_cast<const float4*>(pi + cc);
                                const float4 y = *reinterpret_cast<const float4*>(pj + cc);
                                s += (fabsf(x.x - y.x) + fabsf(x.y - y.y)) +
                                     (fabsf(x.z - y.z) + fabsf(x.w - y.w));
                            }
                            atomicAdd(&outT[(size_t)i * DBx + b], __expf(-s));
                        }
                    }
                }
            }
        }
    }
}

// ---------------------------------------------------------------------------
// logits = sigmoid(concat(feature, outT) @ Wo + bo). One block per row.
// ---------------------------------------------------------------------------
__global__ __launch_bounds__(256) void logits_kernel(const float* __restrict__ feat,
                                                     const float* __restrict__ outT,
                                                     const float* __restrict__ Wo,
                                                     const float* __restrict__ bo,
                                                     float* __restrict__ out2) {
    const int row = blockIdx.x;
    const int t   = threadIdx.x;
    float p = 0.f;
    for (int k = t; k < HD + DBx; k += 256) {
        const float x = (k < HD) ? feat[(size_t)row * HD + k]
                                 : outT[(size_t)row * DBx + (k - HD)];
        p += x * Wo[k];
    }
    #pragma unroll
    for (int off = 32; off; off >>= 1) p += __shfl_down(p, off, 64);
    __shared__ float ws[4];
    if ((t & 63) == 0) ws[t >> 6] = p;
    __syncthreads();
    if (t == 0) {
        const float s = ws[0] + ws[1] + ws[2] + ws[3] + bo[0];
        out2[row] = 1.f / (1.f + __expf(-s));
    }
}

// ---------------------------------------------------------------------------
extern "C" void kernel_launch(void* const* d_in, const int* in_sizes, int n_in,
                              void* d_out, int out_size, void* d_ws, size_t ws_size,
                              hipStream_t stream) {
    const float* input = (const float*)d_in[0];
    const float* W1 = (const float*)d_in[1];
    const float* b1 = (const float*)d_in[2];
    const float* W2 = (const float*)d_in[3];
    const float* b2 = (const float*)d_in[4];
    const float* Wh = (const float*)d_in[5];
    const float* bh = (const float*)d_in[6];
    const float* W3 = (const float*)d_in[7];
    const float* b3 = (const float*)d_in[8];
    const float* W4 = (const float*)d_in[9];
    const float* b4 = (const float*)d_in[10];
    const float* Wo = (const float*)d_in[11];
    const float* bo = (const float*)d_in[12];
    const float* T  = (const float*)d_in[13];

    unsigned short* inbf  = (unsigned short*)d_ws;                 // 2 MB
    unsigned short* W1t   = inbf  + (size_t)2048 * 512;            // 1 MB
    unsigned short* W2t   = W1t   + (size_t)1024 * 512;            // 3 MB
    unsigned short* Wht   = W2t   + (size_t)1536 * 1024;           // 4.5 MB
    unsigned short* W3t   = Wht   + (size_t)1536 * 1536;           // 3 MB
    unsigned short* W4t   = W3t   + (size_t)1024 * 1536;           // 1 MB
    unsigned short* Tt    = W4t   + (size_t)512 * 1024;            // 2 MB
    unsigned short* slabA = Tt    + (size_t)2048 * 512;            // 6 MB
    unsigned short* slabB = slabA + (size_t)2048 * 1536;           // 6 MB
    float* Ms  = (float*)(slabB + (size_t)2048 * 1536);            // 16 MB
    float* oT  = Ms + (size_t)2048 * 2048;                         // 1 MB
    float* nrm = oT + (size_t)2048 * 128;                          // 1 MB
    unsigned short* Msb = inbf;  // 8 MB, region dead by T-GEMM time

    unsigned short* x1bf   = slabA;
    unsigned short* x2bf   = slabB;
    unsigned short* x3bf   = slabA;
    unsigned short* x4bf   = slabB;
    unsigned short* featbf = slabA;

    float* feat = (float*)d_out;
    float* out2 = feat + (size_t)NROWS * HD;

    const dim3 blk(256);

    conv_bf16_kernel<<<1024, blk, 0, stream>>>(input, inbf, 2048 * 512 / 4);

    TransArgs ta;
    ta.src[0] = W1; ta.dst[0] = W1t; ta.K[0] =  512; ta.M[0] = 1024; ta.t0[0] = 0;
    ta.src[1] = W2; ta.dst[1] = W2t; ta.K[1] = 1024; ta.M[1] = 1536; ta.t0[1] = 512;
    ta.src[2] = Wh; ta.dst[2] = Wht; ta.K[2] = 1536; ta.M[2] = 1536; ta.t0[2] = 2048;
    ta.src[3] = W3; ta.dst[3] = W3t; ta.K[3] = 1536; ta.M[3] = 1024; ta.t0[3] = 4352;
    ta.src[4] = W4; ta.dst[4] = W4t; ta.K[4] = 1024; ta.M[4] =  512; ta.t0[4] = 5888;
    ta.src[5] = T;  ta.dst[5] = Tt;  ta.K[5] =  512; ta.M[5] = 2048; ta.t0[5] = 6400;
    trans_all_kernel<<<7424, blk, 0, stream>>>(ta);

    gemm64_kernel<1, 0, 1, 1, 0><<<dim3(1024 / 64, 32), blk, 0, stream>>>(inbf, W1t, b1, x1bf, nullptr, 512, 1024);
    gemm64_kernel<1, 0, 1, 1, 0><<<dim3(1536 / 64, 32), blk, 0, stream>>>(x1bf, W2t, b2, x2bf, nullptr, 1024, 1536);
    gemm64_kernel<1, 0, 1, 1, 0><<<dim3(1536 / 64, 32), blk, 0, stream>>>(x2bf, Wht, bh, x3bf, nullptr, 1536, 1536);
    gemm64_kernel<1, 0, 1, 1, 0><<<dim3(1024 / 64, 32), blk, 0, stream>>>(x3bf, W3t, b3, x4bf, nullptr, 1536, 1024);
    gemm64_kernel<1, 1, 1, 1, 0><<<dim3( 512 / 64, 32), blk, 0, stream>>>(x4bf, W4t, b4, featbf, feat, 1024, 512);
    gemm64_kernel<1, 1, 0, 0, 1><<<dim3(2048 / 64, 32), blk, 0, stream>>>(featbf, Tt, nullptr, Msb, Ms, 512, 2048);

    norms_kernel<<<1024, blk, 0, stream>>>(Ms, nrm, oT);
    mbdisc32_kernel<<<dim3(2, 128, 2), dim3(512), 36864, stream>>>(Ms, Msb, nrm, oT);

    logits_kernel<<<NROWS, blk, 0, stream>>>(feat, oT, Wo, bo, out2);
}